// Round 1
// 207.447 us; speedup vs baseline: 1.0270x; 1.0270x over previous
//
#include <hip/hip_runtime.h>
#include <hip/hip_bf16.h>
#include <math.h>

#define BB 2
#define TT 2048
#define CC 1024
#define HH 16
#define HS 64
#define NROWS (BB * TT)   // 4096
#define QTILES (TT / 64)  // 32

typedef __attribute__((ext_vector_type(8))) short short8v;   // 8 bf16 (4 VGPRs)
typedef __attribute__((ext_vector_type(4))) float f32x4;
typedef __attribute__((ext_vector_type(4))) unsigned int u32x4;
typedef unsigned short u16;

__device__ __forceinline__ float bf2f(u16 b) { return __uint_as_float(((unsigned)b) << 16); }
__device__ __forceinline__ u16 f2bf(float f) {
    return __builtin_bit_cast(u16, (__bf16)f);   // RNE hw cvt (lo-term absorbs residual)
}

// async global->LDS, 16B/lane; LDS dest = wave-uniform base + lane*16
__device__ __forceinline__ void glds16(const void* g, void* l) {
    __builtin_amdgcn_global_load_lds((__attribute__((address_space(1))) void*)g,
                                     (__attribute__((address_space(3))) void*)l, 16, 0, 0);
}
#define WAITV(N) asm volatile("s_waitcnt vmcnt(" #N ")" ::: "memory")
#define BAR() do { __builtin_amdgcn_s_barrier(); __builtin_amdgcn_sched_barrier(0); } while (0)

// ---------------- fused split: x + all 4 weight matrices (one launch) ----------------
__global__ __launch_bounds__(256) void fsplit_kernel(const float* __restrict__ x,
                                                     const float* __restrict__ Wq, const float* __restrict__ Wk,
                                                     const float* __restrict__ Wv, const float* __restrict__ Wp,
                                                     u16* __restrict__ xh, u16* __restrict__ xl,
                                                     u16* __restrict__ qk,   // d_out: [Wq_h|Wk_h|Wq_l|Wk_l]
                                                     u16* __restrict__ wvh, u16* __restrict__ wvl,
                                                     u16* __restrict__ wph, u16* __restrict__ wpl) {
    const size_t WC = (size_t)CC * CC;
    const int bid = blockIdx.x;
    const float* src; u16 *dh, *dl; float sc = 1.f; int i;
    if (bid < 4096) {            // x split: 4M elements / 4 per thread
        src = x; dh = xh; dl = xl; i = bid * 256 + threadIdx.x;
    } else {
        const int wsel = (bid - 4096) >> 10;
        i = ((bid - 4096) & 1023) * 256 + threadIdx.x;
        // fold 1/8 AND log2(e) into Wq: attn softmax then uses a single v_exp_f32 (exp2)
        if (wsel == 0)      { src = Wq; dh = qk;      dl = qk + 2 * WC; sc = 0.125f * 1.4426950408889634f; }
        else if (wsel == 1) { src = Wk; dh = qk + WC; dl = qk + 3 * WC; }
        else if (wsel == 2) { src = Wv; dh = wvh;     dl = wvl; }
        else                { src = Wp; dh = wph;     dl = wpl; }
    }
    float4 v = ((const float4*)src)[i];
    v.x *= sc; v.y *= sc; v.z *= sc; v.w *= sc;
    ushort4 H, L;
    H.x = f2bf(v.x); L.x = f2bf(v.x - bf2f(H.x));
    H.y = f2bf(v.y); L.y = f2bf(v.y - bf2f(H.y));
    H.z = f2bf(v.z); L.z = f2bf(v.z - bf2f(H.z));
    H.w = f2bf(v.w); L.w = f2bf(v.w - bf2f(H.w));
    ((ushort4*)dh)[i] = H;
    ((ushort4*)dl)[i] = L;
}

// ---------------- split-bf16 MFMA GEMM, pipelined (1 bar/step, counted vmcnt) ----------------
// OM=0: fp32 out (stride N). OM=1: split bf16 out, col<CC -> O1 else O2 (stride CC).
// OM=2: transposed V^T epilogue -> O1h/O1l = Vt[bh][d][t] splits + per-tile colsum TSg.
template<int GNT, int OM>
__global__ __launch_bounds__(256) void gemm_mfma(const u16* __restrict__ Ah, const u16* __restrict__ Al,
                                                 const u16* __restrict__ Bh, const u16* __restrict__ Bl,
                                                 float* __restrict__ O,
                                                 u16* __restrict__ O1h, u16* __restrict__ O1l,
                                                 u16* __restrict__ O2h, u16* __restrict__ O2l,
                                                 float* __restrict__ TSg,
                                                 int M, int N, int K) {
    constexpr int NI = GNT / 32;                   // B frags per wave
    constexpr int BCH = (GNT == 128) ? 512 : 256;  // B buffer chunk count
    __shared__ u16 lAh[2 * 4096], lAl[2 * 4096], lBh[2 * GNT * 32], lBl[2 * GNT * 32];
    const int tid = threadIdx.x;
    const int lane = tid & 63, w = tid >> 6;
    const int wr = w >> 1, wc = w & 1;
    const int fr = lane & 15, fc = lane >> 4;

    const int nbx = gridDim.x;
    const int bid = blockIdx.y * nbx + blockIdx.x;
    const int nwg = nbx * gridDim.y;
    const int swz = (bid & 7) * (nwg >> 3) + (bid >> 3);
    const int bm = (swz / nbx) * 128, bn = (swz % nbx) * GNT;

    f32x4 acc[4][NI];
    #pragma unroll
    for (int i = 0; i < 4; ++i)
        #pragma unroll
        for (int j = 0; j < NI; ++j) acc[i][j] = (f32x4){0.f, 0.f, 0.f, 0.f};

    const int lrow = lane >> 2, lcs = lane & 3;
    const int rA0 = w * 16 + lrow, rA1 = rA0 + 64;
    const size_t aoff0 = (size_t)(bm + rA0) * K + (lcs ^ ((rA0 >> 1) & 3)) * 8;
    const size_t aoff1 = (size_t)(bm + rA1) * K + (lcs ^ ((rA1 >> 1) & 3)) * 8;
    const size_t boff0 = (size_t)(bn + rA0) * K + (lcs ^ ((rA0 >> 1) & 3)) * 8;
    size_t boff1 = 0;
    if constexpr (GNT == 128) boff1 = (size_t)(bn + rA1) * K + (lcs ^ ((rA1 >> 1) & 3)) * 8;
    const int d0 = w * 512, d1 = 2048 + w * 512;

    int aslot[4], bslot[NI];
    #pragma unroll
    for (int mi = 0; mi < 4; ++mi) {
        int row = wr * 64 + mi * 16 + fr;
        aslot[mi] = row * 4 + (fc ^ ((row >> 1) & 3));
    }
    #pragma unroll
    for (int ni = 0; ni < NI; ++ni) {
        int col = wc * (GNT / 2) + ni * 16 + fr;
        bslot[ni] = col * 4 + (fc ^ ((col >> 1) & 3));
    }

    auto STAGE = [&](int t, int buf) {
        const int k0 = t * 32;
        const int bo = buf * 4096;
        glds16(Ah + aoff0 + k0, lAh + bo + d0);
        glds16(Ah + aoff1 + k0, lAh + bo + d1);
        glds16(Al + aoff0 + k0, lAl + bo + d0);
        glds16(Al + aoff1 + k0, lAl + bo + d1);
        if constexpr (GNT == 128) {
            glds16(Bh + boff0 + k0, lBh + bo + d0);
            glds16(Bh + boff1 + k0, lBh + bo + d1);
            glds16(Bl + boff0 + k0, lBl + bo + d0);
            glds16(Bl + boff1 + k0, lBl + bo + d1);
        } else {
            const int bo2 = buf * 2048;
            glds16(Bh + boff0 + k0, lBh + bo2 + d0);
            glds16(Bl + boff0 + k0, lBl + bo2 + d0);
        }
    };

    const int nt = K >> 5;
    STAGE(0, 0);

    #pragma unroll 2
    for (int t = 0; t < nt; ++t) {
        const int cur = t & 1;
        BAR();   // prev iter's readers of buf[cur^1] are done -> safe to overwrite
        if (t + 1 < nt) {
            STAGE(t + 1, cur ^ 1);
            if constexpr (GNT == 128) { WAITV(8); } else { WAITV(6); }  // tile t landed
        } else {
            WAITV(0);
        }

        const int co = cur * 512, co2 = cur * BCH;
        short8v fah[4], fal[4], fbh[NI], fbl[NI];
        #pragma unroll
        for (int mi = 0; mi < 4; ++mi) {
            fah[mi] = ((const short8v*)lAh)[co + aslot[mi]];
            fal[mi] = ((const short8v*)lAl)[co + aslot[mi]];
        }
        #pragma unroll
        for (int ni = 0; ni < NI; ++ni) {
            fbh[ni] = ((const short8v*)lBh)[co2 + bslot[ni]];
            fbl[ni] = ((const short8v*)lBl)[co2 + bslot[ni]];
        }
        __builtin_amdgcn_s_setprio(1);
        #pragma unroll
        for (int mi = 0; mi < 4; ++mi)
            #pragma unroll
            for (int ni = 0; ni < NI; ++ni) {
                acc[mi][ni] = __builtin_amdgcn_mfma_f32_16x16x32_bf16(fah[mi], fbh[ni], acc[mi][ni], 0, 0, 0);
                acc[mi][ni] = __builtin_amdgcn_mfma_f32_16x16x32_bf16(fah[mi], fbl[ni], acc[mi][ni], 0, 0, 0);
                acc[mi][ni] = __builtin_amdgcn_mfma_f32_16x16x32_bf16(fal[mi], fbh[ni], acc[mi][ni], 0, 0, 0);
            }
        __builtin_amdgcn_s_setprio(0);
    }

    const int fq = lane >> 4;
    #pragma unroll
    for (int mi = 0; mi < 4; ++mi)
        #pragma unroll
        for (int ni = 0; ni < NI; ++ni)
            #pragma unroll
            for (int r = 0; r < 4; ++r) {
                const int rg = bm + wr * 64 + mi * 16 + fq * 4 + r;
                const int cg = bn + wc * (GNT / 2) + ni * 16 + fr;
                const float v = acc[mi][ni][r];
                if constexpr (OM == 0) {
                    O[(size_t)rg * N + cg] = v;
                } else {
                    const u16 hh = f2bf(v);
                    const u16 ll = f2bf(v - bf2f(hh));
                    if constexpr (OM == 1) {
                        if (cg < CC) {
                            O1h[(size_t)rg * CC + cg] = hh;
                            O1l[(size_t)rg * CC + cg] = ll;
                        } else {
                            O2h[(size_t)rg * CC + cg - CC] = hh;
                            O2l[(size_t)rg * CC + cg - CC] = ll;
                        }
                    } else {  // OM == 2: O = V^T; rg = h*64+d, cg = b*2048+t
                        const int bq = cg >> 11, tq = cg & 2047;
                        const int hq = rg >> 6, dq = rg & 63;
                        const size_t o = ((size_t)((bq << 4) + hq) * HS + dq) * TT + tq;
                        O1h[o] = hh; O1l[o] = ll;
                    }
                }
            }

    if constexpr (OM == 2) {
        // per-tile column sums: this block covers one (b, qt) x 128 d-rows
        __syncthreads();                 // all LDS frag reads done -> reuse lAh
        float* TSL = (float*)lAh;        // 256 floats
        #pragma unroll
        for (int mi = 0; mi < 4; ++mi)
            #pragma unroll
            for (int r = 0; r < 4; ++r) {
                float s = acc[mi][0][r] + acc[mi][1][r];
                s += __shfl_xor(s, 1); s += __shfl_xor(s, 2);
                s += __shfl_xor(s, 4); s += __shfl_xor(s, 8);
                if (fr == 0) TSL[wc * 128 + wr * 64 + mi * 16 + fq * 4 + r] = s;
            }
        __syncthreads();
        if (tid < 128) {
            const float ts = TSL[tid] + TSL[128 + tid];
            const int bq = bn >> 11;
            const int qt = (bn & 2047) >> 6;
            const int bhh = (bq << 4) + ((bm + tid) >> 6);
            const int dq = (bm + tid) & 63;
            TSg[((size_t)bhh * QTILES + qt) * 64 + dq] = ts;
        }
    }
}

// ---------------- suffix scan over tile sums -> STile ----------------
__global__ __launch_bounds__(64) void scan_kernel(const float* __restrict__ TSg,
                                                  float* __restrict__ STile) {
    const int bh = blockIdx.x;
    const int d = threadIdx.x;
    float s = 0.f;
    STile[((size_t)bh * 33 + 32) * 64 + d] = 0.f;
    for (int qt = QTILES - 1; qt >= 0; --qt) {
        s += TSg[((size_t)bh * QTILES + qt) * 64 + d];
        STile[((size_t)bh * 33 + qt) * 64 + d] = s;
    }
}

// ---------------- MFMA flash attention: 64-q paired tiles, K+V dbuf, swapped QK^T ----------------
// 4 waves; wave w owns q-rows [w*16, w*16+16) of a 64-q tile. Paired {31-p, p}:
// uniform 33 k-tiles per block. Static max M=0; -U folded into y via negated causal
// ones MFMA on the diagonal tile; + STile at the end.
// QK^T computes mfma(K, Q) = S^T so each lane holds P[key=j*16+hi4*4+r][q=lx]:
// adjacent r = adjacent keys -> hi/lo bf16 pairs pack in-register, P goes to LDS as
// ds_write_b64 and comes back as ds_read_b128 A-frags with ZERO repack ALU.
__global__ __launch_bounds__(256, 2) void attn_kernel(const u16* __restrict__ Qh, const u16* __restrict__ Ql,
                                                      const u16* __restrict__ Kh, const u16* __restrict__ Kl,
                                                      const u16* __restrict__ Vth, const u16* __restrict__ Vtl,
                                                      const float* __restrict__ STile,
                                                      u16* __restrict__ Yh, u16* __restrict__ Yl) {
    const int g = blockIdx.x;            // 512
    const int xcd = g & 7;
    const int idx = g >> 3;
    const int bh = xcd + 8 * (idx & 3);  // bh locked to one XCD
    const int p = idx >> 2;              // 0..15
    const int b = bh >> 4, h = bh & 15;
    const int tid = threadIdx.x;
    const int w = tid >> 6, lane = tid & 63;
    const int lx = lane & 15, hi4 = lane >> 4;

    __shared__ u16 Ksh[2 * 4096], Ksl[2 * 4096];   // 32KB: K dbuf
    __shared__ u16 Vsh[2 * 4096], Vsl[2 * 4096];   // 32KB: V dbuf
    __shared__ unsigned Pph[4][512], Ppl[4][512];  // 16KB: P hi/lo bf16-pairs, per wave
    unsigned* const Pwh = Pph[w];
    unsigned* const Pwl = Ppl[w];

    const u16* Kgh = Kh + (size_t)b * TT * CC + h * HS;
    const u16* Kgl = Kl + (size_t)b * TT * CC + h * HS;
    const u16* Vgh = Vth + (size_t)bh * HS * TT;
    const u16* Vgl = Vtl + (size_t)bh * HS * TT;

    // staging geometry: chunk s = uu*256 + w*64 + lane; linear dest, source col pre-swizzled
    const int s0 = w * 64 + lane, s1 = 256 + w * 64 + lane;
    const int rr0 = s0 >> 3, gc0 = (s0 & 7) ^ (rr0 & 7);
    const int rr1 = s1 >> 3, gc1 = (s1 & 7) ^ (rr1 & 7);
    const int db0 = (w * 64) * 8, db1 = (256 + w * 64) * 8;
    const size_t kbase0 = (size_t)rr0 * CC + gc0 * 8;
    const size_t kbase1 = (size_t)rr1 * CC + gc1 * 8;
    const size_t vbase0 = (size_t)rr0 * TT + gc0 * 8;
    const size_t vbase1 = (size_t)rr1 * TT + gc1 * 8;

    auto stage = [&](int kt, int buf) {
        const size_t ko = (size_t)kt * 64 * CC;
        const int vo = kt * 64;
        const int bo = buf * 4096;
        glds16(Kgh + ko + kbase0, Ksh + bo + db0);
        glds16(Kgh + ko + kbase1, Ksh + bo + db1);
        glds16(Kgl + ko + kbase0, Ksl + bo + db0);
        glds16(Kgl + ko + kbase1, Ksl + bo + db1);
        glds16(Vgh + vbase0 + vo, Vsh + bo + db0);
        glds16(Vgh + vbase1 + vo, Vsh + bo + db1);
        glds16(Vgl + vbase0 + vo, Vsl + bo + db0);
        glds16(Vgl + vbase1 + vo, Vsl + bo + db1);
    };

    // NEGATED causal-inclusive ones A-frags (fold -U into y on the diagonal tile)
    short8v nones[2];
    #pragma unroll
    for (int k0 = 0; k0 < 2; ++k0)
        #pragma unroll
        for (int jj = 0; jj < 8; ++jj)
            nones[k0][jj] = (short)(((k0 * 32 + hi4 * 8 + jj) <= (w * 16 + lx)) ? 0xBF80 : 0);

    // P pair-swizzle: row q (stride 32 u32), pair' = pair ^ s(q), s(q)=4*q0 ^ 8*(q1^q3) ^ 16*q2.
    // Conflict-free for the b64 writes (per-(j) instr: 4 words/bank over a 2-cycle floor)
    // and the b128 frag reads (2 lanes per 4-bank quad within each 16-lane group).
    const int sxz = ((lx & 1) << 2) ^ ((((lx >> 1) ^ (lx >> 3)) & 1) << 3) ^ (((lx >> 2) & 1) << 4);
    int wIdx[4];
    #pragma unroll
    for (int j = 0; j < 4; ++j) wIdx[j] = lx * 32 + ((8 * j + 2 * hi4) ^ sxz);
    const int rIdx[2] = {lx * 32 + ((4 * hi4) ^ sxz), lx * 32 + ((16 + 4 * hi4) ^ sxz)};

    const f32x4 zero = {0.f, 0.f, 0.f, 0.f};
    int cur = 0;
    for (int half = 0; half < 2; ++half) {
        const int qt = half ? p : (31 - p);

        stage(0, cur);   // safe: buf[cur]'s last readers finished 2 barriers ago

        const size_t qoff = (size_t)(b * TT + qt * 64 + w * 16 + lx) * CC + h * HS + hi4 * 8;
        short8v qfh[2], qfl[2];
        qfh[0] = *(const short8v*)(Qh + qoff); qfh[1] = *(const short8v*)(Qh + qoff + 32);
        qfl[0] = *(const short8v*)(Ql + qoff); qfl[1] = *(const short8v*)(Ql + qoff + 32);

        f32x4 y4[4];
        float lsum = 0.f;
        #pragma unroll
        for (int dt = 0; dt < 4; ++dt) y4[dt] = zero;

        for (int kt = 0; kt <= qt; ++kt) {
            BAR();   // prev iter's readers of buf[cur^1] done -> stage may overwrite
            if (kt < qt) { stage(kt + 1, cur ^ 1); WAITV(8); }
            else         { WAITV(0); }

            const int co = cur * 512;
            const bool diag = (kt == qt);

            // ---- QK^T (swapped: A=K, B=Q -> D = S^T) ----
            f32x4 s4[4];
            #pragma unroll
            for (int j = 0; j < 4; ++j) s4[j] = zero;
            __builtin_amdgcn_s_setprio(1);
            #pragma unroll
            for (int j = 0; j < 4; ++j) {
                const int keyr = j * 16 + lx;
                const int rb = keyr * 8, sw = keyr & 7;
                #pragma unroll
                for (int d0 = 0; d0 < 2; ++d0) {
                    const int sl = co + rb + ((hi4 + 4 * d0) ^ sw);
                    const short8v kbh = ((const short8v*)Ksh)[sl];
                    const short8v kbl = ((const short8v*)Ksl)[sl];
                    s4[j] = __builtin_amdgcn_mfma_f32_16x16x32_bf16(kbh, qfh[d0], s4[j], 0, 0, 0);
                    s4[j] = __builtin_amdgcn_mfma_f32_16x16x32_bf16(kbh, qfl[d0], s4[j], 0, 0, 0);
                    s4[j] = __builtin_amdgcn_mfma_f32_16x16x32_bf16(kbl, qfh[d0], s4[j], 0, 0, 0);
                }
            }
            __builtin_amdgcn_s_setprio(0);

            // ---- softmax (static M=0): lane holds P[key=j*16+hi4*4+r][q=lx] ----
            // Wq pre-scaled by log2e -> exp2 is a single v_exp_f32; masked-0 quirk handled
            // by -U fold (exp2(0)=1 for masked entries regardless of scaling).
            #pragma unroll
            for (int j = 0; j < 4; ++j) {
                float pv[4];
                #pragma unroll
                for (int r = 0; r < 4; ++r) {
                    float e = __builtin_amdgcn_exp2f(s4[j][r]);
                    if (diag && (j * 16 + hi4 * 4 + r) > (w * 16 + lx)) e = 0.f;
                    lsum += e;
                    pv[r] = e;
                }
                const u16 p0 = f2bf(pv[0]), p1 = f2bf(pv[1]), p2 = f2bf(pv[2]), p3 = f2bf(pv[3]);
                uint2 HW, LW;
                HW.x = (unsigned)p0 | ((unsigned)p1 << 16);
                HW.y = (unsigned)p2 | ((unsigned)p3 << 16);
                LW.x = (unsigned)f2bf(pv[0] - bf2f(p0)) | ((unsigned)f2bf(pv[1] - bf2f(p1)) << 16);
                LW.y = (unsigned)f2bf(pv[2] - bf2f(p2)) | ((unsigned)f2bf(pv[3] - bf2f(p3)) << 16);
                *(uint2*)(Pwh + wIdx[j]) = HW;
                *(uint2*)(Pwl + wIdx[j]) = LW;
            }
            // A-frags: direct b128 reads, zero repack (same-wave write->read, lgkm-ordered)
            short8v pah[2], pal[2];
            #pragma unroll
            for (int k0 = 0; k0 < 2; ++k0) {
                pah[k0] = __builtin_bit_cast(short8v, *(const u32x4*)(Pwh + rIdx[k0]));
                pal[k0] = __builtin_bit_cast(short8v, *(const u32x4*)(Pwl + rIdx[k0]));
            }

            // ---- PV (+ negated causal-ones on the diagonal tile) ----
            __builtin_amdgcn_s_setprio(1);
            #pragma unroll
            for (int dt = 0; dt < 4; ++dt) {
                const int drow = dt * 16 + lx;
                const int rb = drow * 8, sw = drow & 7;
                #pragma unroll
                for (int k0 = 0; k0 < 2; ++k0) {
                    const int sl = co + rb + ((hi4 + 4 * k0) ^ sw);
                    const short8v vbh = ((const short8v*)Vsh)[sl];
                    const short8v vbl = ((const short8v*)Vsl)[sl];
                    y4[dt] = __builtin_amdgcn_mfma_f32_16x16x32_bf16(pah[k0], vbh, y4[dt], 0, 0, 0);
                    y4[dt] = __builtin_amdgcn_mfma_f32_16x16x32_bf16(pal[k0], vbh, y4[dt], 0, 0, 0);
                    y4[dt] = __builtin_amdgcn_mfma_f32_16x16x32_bf16(pah[k0], vbl, y4[dt], 0, 0, 0);
                    if (diag) {
                        y4[dt] = __builtin_amdgcn_mfma_f32_16x16x32_bf16(nones[k0], vbh, y4[dt], 0, 0, 0);
                        y4[dt] = __builtin_amdgcn_mfma_f32_16x16x32_bf16(nones[k0], vbl, y4[dt], 0, 0, 0);
                    }
                }
            }
            __builtin_amdgcn_s_setprio(0);

            cur ^= 1;
        }

        // ---- l reduce: lsum is per-lane (q=lx); sum hi4 groups, redistribute to (hi4,r) ----
        lsum += __shfl_xor(lsum, 16);
        lsum += __shfl_xor(lsum, 32);
        float l4[4];
        #pragma unroll
        for (int r = 0; r < 4; ++r) l4[r] = __shfl(lsum, hi4 * 4 + r);

        // ---- masked-zero tail: y holds (PV - U); add STile, normalize ----
        const float* stp = STile + ((size_t)bh * 33 + qt) * 64;
        #pragma unroll
        for (int dt = 0; dt < 4; ++dt) {
            const float st = stp[dt * 16 + lx];
            #pragma unroll
            for (int r = 0; r < 4; ++r) {
                const int t = qt * 64 + w * 16 + hi4 * 4 + r;
                const float linv = 1.f / (l4[r] + (float)(TT - 1 - t));
                const float yv = (y4[dt][r] + st) * linv;
                const u16 hh = f2bf(yv);
                const u16 l2 = f2bf(yv - bf2f(hh));
                const size_t off = (size_t)(b * TT + t) * CC + h * HS + dt * 16 + lx;
                Yh[off] = hh; Yl[off] = l2;
            }
        }
    }
}

// ---------------- launch ----------------
extern "C" void kernel_launch(void* const* d_in, const int* in_sizes, int n_in,
                              void* d_out, int out_size, void* d_ws, size_t ws_size,
                              hipStream_t stream) {
    const float* x  = (const float*)d_in[0];
    const float* Wq = (const float*)d_in[1];
    const float* Wk = (const float*)d_in[2];
    const float* Wv = (const float*)d_in[3];
    const float* Wp = (const float*)d_in[4];
    float* out = (float*)d_out;

    const size_t NC = (size_t)NROWS * CC;       // 4M elements
    const size_t WC = (size_t)CC * CC;          // 1M elements
    char* ws = (char*)d_ws;
    // [0,16MB): x splits; after Vt-GEMM x is dead -> Y splits
    u16* xh = (u16*)ws;                  u16* xl = xh + NC;
    u16* Yh = xh;                        u16* Yl = xl;
    // [16,32MB): Q splits
    u16* Qh = (u16*)(ws + (16u << 20));  u16* Ql = Qh + NC;
    // [32,48MB): K splits
    u16* Kh = (u16*)(ws + (32u << 20));  u16* Kl = Kh + NC;
    // [48,52MB): Wv splits (dead after Vt GEMM); [52,52.25MB): TSg (dead after scan)
    u16* wvh = (u16*)(ws + (48u << 20)); u16* wvl = wvh + WC;
    float* TSg = (float*)(ws + (52u << 20));   // 32*32*64 floats = 256KB
    // [56,64MB): Wp splits
    u16* wph = (u16*)(ws + (56u << 20)); u16* wpl = wph + WC;
    // [64MB,+270KB): STile
    float* St = (float*)(ws + (64u << 20));
    // d_out (16MB): first wqk splits, then Vt splits, finally the real output
    u16* wqk = (u16*)out;
    u16* Vth = (u16*)out;                u16* Vtl = Vth + NC;

    fsplit_kernel<<<8192, 256, 0, stream>>>(x, Wq, Wk, Wv, Wp, xh, xl, wqk, wvh, wvl, wph, wpl);

    // fused Q+K GEMM: N=2048, 128x128 tiles -> 512 blocks
    gemm_mfma<128, 1><<<dim3(2048 / 128, NROWS / 128), 256, 0, stream>>>(
        xh, xl, wqk, wqk + 2 * WC, nullptr, Qh, Ql, Kh, Kl, nullptr, NROWS, 2048, CC);

    // V^T GEMM: A=Wv (M=1024), B=x (N=4096) -> Vt splits in d_out + per-tile colsums
    gemm_mfma<64, 2><<<dim3(NROWS / 64, CC / 128), 256, 0, stream>>>(
        wvh, wvl, xh, xl, nullptr, Vth, Vtl, nullptr, nullptr, TSg, CC, NROWS, CC);

    scan_kernel<<<BB * HH, 64, 0, stream>>>(TSg, St);

    attn_kernel<<<512, 256, 0, stream>>>(Qh, Ql, Kh, Kl, Vth, Vtl, St, Yh, Yl);

    // output projection (overwrites d_out; Vt is dead)
    gemm_mfma<64, 0><<<dim3(CC / 64, NROWS / 128), 256, 0, stream>>>(
        Yh, Yl, wph, wpl, out, nullptr, nullptr, nullptr, nullptr, nullptr, NROWS, CC, CC);
}

// Round 2
// 204.744 us; speedup vs baseline: 1.0405x; 1.0132x over previous
//
#include <hip/hip_runtime.h>
#include <hip/hip_bf16.h>
#include <math.h>

#define BB 2
#define TT 2048
#define CC 1024
#define HH 16
#define HS 64
#define NROWS (BB * TT)   // 4096
#define QTILES (TT / 64)  // 32

typedef __attribute__((ext_vector_type(8))) short short8v;   // 8 bf16 (4 VGPRs)
typedef __attribute__((ext_vector_type(4))) float f32x4;
typedef __attribute__((ext_vector_type(4))) unsigned int u32x4;
typedef unsigned short u16;

__device__ __forceinline__ float bf2f(u16 b) { return __uint_as_float(((unsigned)b) << 16); }
__device__ __forceinline__ u16 f2bf(float f) {
    return __builtin_bit_cast(u16, (__bf16)f);   // RNE hw cvt (lo-term absorbs residual)
}

// async global->LDS, 16B/lane; LDS dest = wave-uniform base + lane*16
__device__ __forceinline__ void glds16(const void* g, void* l) {
    __builtin_amdgcn_global_load_lds((__attribute__((address_space(1))) void*)g,
                                     (__attribute__((address_space(3))) void*)l, 16, 0, 0);
}
#define WAITV(N) asm volatile("s_waitcnt vmcnt(" #N ")" ::: "memory")
#define BAR() do { __builtin_amdgcn_s_barrier(); __builtin_amdgcn_sched_barrier(0); } while (0)

// cross-lane half-swaps (gfx950): after swap32(a,b): a = {a.lo32, b.lo32}, b = {a.hi32, b.hi32}
__device__ __forceinline__ void swap32(unsigned& a, unsigned& b) {
    asm volatile("v_permlane32_swap_b32 %0, %1" : "+v"(a), "+v"(b));
}
// swap16: exchange a's odd 16-lane groups with b's even groups:
// a = {a.g0, b.g0, a.g2, b.g2}, b = {a.g1, b.g1, a.g3, b.g3}
__device__ __forceinline__ void swap16(unsigned& a, unsigned& b) {
    asm volatile("v_permlane16_swap_b32 %0, %1" : "+v"(a), "+v"(b));
}

// ---------------- fused split: x + all 4 weight matrices (one launch) ----------------
__global__ __launch_bounds__(256) void fsplit_kernel(const float* __restrict__ x,
                                                     const float* __restrict__ Wq, const float* __restrict__ Wk,
                                                     const float* __restrict__ Wv, const float* __restrict__ Wp,
                                                     u16* __restrict__ xh, u16* __restrict__ xl,
                                                     u16* __restrict__ qk,   // d_out: [Wq_h|Wk_h|Wq_l|Wk_l]
                                                     u16* __restrict__ wvh, u16* __restrict__ wvl,
                                                     u16* __restrict__ wph, u16* __restrict__ wpl) {
    const size_t WC = (size_t)CC * CC;
    const int bid = blockIdx.x;
    const float* src; u16 *dh, *dl; float sc = 1.f; int i;
    if (bid < 4096) {            // x split: 4M elements / 4 per thread
        src = x; dh = xh; dl = xl; i = bid * 256 + threadIdx.x;
    } else {
        const int wsel = (bid - 4096) >> 10;
        i = ((bid - 4096) & 1023) * 256 + threadIdx.x;
        // fold 1/8 AND log2(e) into Wq: attn softmax then uses a single v_exp_f32 (exp2)
        if (wsel == 0)      { src = Wq; dh = qk;      dl = qk + 2 * WC; sc = 0.125f * 1.4426950408889634f; }
        else if (wsel == 1) { src = Wk; dh = qk + WC; dl = qk + 3 * WC; }
        else if (wsel == 2) { src = Wv; dh = wvh;     dl = wvl; }
        else                { src = Wp; dh = wph;     dl = wpl; }
    }
    float4 v = ((const float4*)src)[i];
    v.x *= sc; v.y *= sc; v.z *= sc; v.w *= sc;
    ushort4 H, L;
    H.x = f2bf(v.x); L.x = f2bf(v.x - bf2f(H.x));
    H.y = f2bf(v.y); L.y = f2bf(v.y - bf2f(H.y));
    H.z = f2bf(v.z); L.z = f2bf(v.z - bf2f(H.z));
    H.w = f2bf(v.w); L.w = f2bf(v.w - bf2f(H.w));
    ((ushort4*)dh)[i] = H;
    ((ushort4*)dl)[i] = L;
}

// ---------------- split-bf16 MFMA GEMM, pipelined (1 bar/step, counted vmcnt) ----------------
// OM=0: fp32 out (stride N). OM=1: split bf16 out, col<CC -> O1 else O2 (stride CC).
// OM=2: transposed V^T epilogue -> O1h/O1l = Vt[bh][d][t] splits + per-tile colsum TSg.
template<int GNT, int OM>
__global__ __launch_bounds__(256) void gemm_mfma(const u16* __restrict__ Ah, const u16* __restrict__ Al,
                                                 const u16* __restrict__ Bh, const u16* __restrict__ Bl,
                                                 float* __restrict__ O,
                                                 u16* __restrict__ O1h, u16* __restrict__ O1l,
                                                 u16* __restrict__ O2h, u16* __restrict__ O2l,
                                                 float* __restrict__ TSg,
                                                 int M, int N, int K) {
    constexpr int NI = GNT / 32;                   // B frags per wave
    constexpr int BCH = (GNT == 128) ? 512 : 256;  // B buffer chunk count
    __shared__ u16 lAh[2 * 4096], lAl[2 * 4096], lBh[2 * GNT * 32], lBl[2 * GNT * 32];
    const int tid = threadIdx.x;
    const int lane = tid & 63, w = tid >> 6;
    const int wr = w >> 1, wc = w & 1;
    const int fr = lane & 15, fc = lane >> 4;

    const int nbx = gridDim.x;
    const int bid = blockIdx.y * nbx + blockIdx.x;
    const int nwg = nbx * gridDim.y;
    const int swz = (bid & 7) * (nwg >> 3) + (bid >> 3);
    const int bm = (swz / nbx) * 128, bn = (swz % nbx) * GNT;

    f32x4 acc[4][NI];
    #pragma unroll
    for (int i = 0; i < 4; ++i)
        #pragma unroll
        for (int j = 0; j < NI; ++j) acc[i][j] = (f32x4){0.f, 0.f, 0.f, 0.f};

    const int lrow = lane >> 2, lcs = lane & 3;
    const int rA0 = w * 16 + lrow, rA1 = rA0 + 64;
    const size_t aoff0 = (size_t)(bm + rA0) * K + (lcs ^ ((rA0 >> 1) & 3)) * 8;
    const size_t aoff1 = (size_t)(bm + rA1) * K + (lcs ^ ((rA1 >> 1) & 3)) * 8;
    const size_t boff0 = (size_t)(bn + rA0) * K + (lcs ^ ((rA0 >> 1) & 3)) * 8;
    size_t boff1 = 0;
    if constexpr (GNT == 128) boff1 = (size_t)(bn + rA1) * K + (lcs ^ ((rA1 >> 1) & 3)) * 8;
    const int d0 = w * 512, d1 = 2048 + w * 512;

    int aslot[4], bslot[NI];
    #pragma unroll
    for (int mi = 0; mi < 4; ++mi) {
        int row = wr * 64 + mi * 16 + fr;
        aslot[mi] = row * 4 + (fc ^ ((row >> 1) & 3));
    }
    #pragma unroll
    for (int ni = 0; ni < NI; ++ni) {
        int col = wc * (GNT / 2) + ni * 16 + fr;
        bslot[ni] = col * 4 + (fc ^ ((col >> 1) & 3));
    }

    auto STAGE = [&](int t, int buf) {
        const int k0 = t * 32;
        const int bo = buf * 4096;
        glds16(Ah + aoff0 + k0, lAh + bo + d0);
        glds16(Ah + aoff1 + k0, lAh + bo + d1);
        glds16(Al + aoff0 + k0, lAl + bo + d0);
        glds16(Al + aoff1 + k0, lAl + bo + d1);
        if constexpr (GNT == 128) {
            glds16(Bh + boff0 + k0, lBh + bo + d0);
            glds16(Bh + boff1 + k0, lBh + bo + d1);
            glds16(Bl + boff0 + k0, lBl + bo + d0);
            glds16(Bl + boff1 + k0, lBl + bo + d1);
        } else {
            const int bo2 = buf * 2048;
            glds16(Bh + boff0 + k0, lBh + bo2 + d0);
            glds16(Bl + boff0 + k0, lBl + bo2 + d0);
        }
    };

    const int nt = K >> 5;
    STAGE(0, 0);

    #pragma unroll 2
    for (int t = 0; t < nt; ++t) {
        const int cur = t & 1;
        BAR();   // prev iter's readers of buf[cur^1] are done -> safe to overwrite
        if (t + 1 < nt) {
            STAGE(t + 1, cur ^ 1);
            if constexpr (GNT == 128) { WAITV(8); } else { WAITV(6); }  // tile t landed
        } else {
            WAITV(0);
        }

        const int co = cur * 512, co2 = cur * BCH;
        short8v fah[4], fal[4], fbh[NI], fbl[NI];
        #pragma unroll
        for (int mi = 0; mi < 4; ++mi) {
            fah[mi] = ((const short8v*)lAh)[co + aslot[mi]];
            fal[mi] = ((const short8v*)lAl)[co + aslot[mi]];
        }
        #pragma unroll
        for (int ni = 0; ni < NI; ++ni) {
            fbh[ni] = ((const short8v*)lBh)[co2 + bslot[ni]];
            fbl[ni] = ((const short8v*)lBl)[co2 + bslot[ni]];
        }
        __builtin_amdgcn_s_setprio(1);
        #pragma unroll
        for (int mi = 0; mi < 4; ++mi)
            #pragma unroll
            for (int ni = 0; ni < NI; ++ni) {
                acc[mi][ni] = __builtin_amdgcn_mfma_f32_16x16x32_bf16(fah[mi], fbh[ni], acc[mi][ni], 0, 0, 0);
                acc[mi][ni] = __builtin_amdgcn_mfma_f32_16x16x32_bf16(fah[mi], fbl[ni], acc[mi][ni], 0, 0, 0);
                acc[mi][ni] = __builtin_amdgcn_mfma_f32_16x16x32_bf16(fal[mi], fbh[ni], acc[mi][ni], 0, 0, 0);
            }
        __builtin_amdgcn_s_setprio(0);
    }

    const int fq = lane >> 4;
    #pragma unroll
    for (int mi = 0; mi < 4; ++mi)
        #pragma unroll
        for (int ni = 0; ni < NI; ++ni)
            #pragma unroll
            for (int r = 0; r < 4; ++r) {
                const int rg = bm + wr * 64 + mi * 16 + fq * 4 + r;
                const int cg = bn + wc * (GNT / 2) + ni * 16 + fr;
                const float v = acc[mi][ni][r];
                if constexpr (OM == 0) {
                    O[(size_t)rg * N + cg] = v;
                } else {
                    const u16 hh = f2bf(v);
                    const u16 ll = f2bf(v - bf2f(hh));
                    if constexpr (OM == 1) {
                        if (cg < CC) {
                            O1h[(size_t)rg * CC + cg] = hh;
                            O1l[(size_t)rg * CC + cg] = ll;
                        } else {
                            O2h[(size_t)rg * CC + cg - CC] = hh;
                            O2l[(size_t)rg * CC + cg - CC] = ll;
                        }
                    } else {  // OM == 2: O = V^T; rg = h*64+d, cg = b*2048+t
                        const int bq = cg >> 11, tq = cg & 2047;
                        const int hq = rg >> 6, dq = rg & 63;
                        const size_t o = ((size_t)((bq << 4) + hq) * HS + dq) * TT + tq;
                        O1h[o] = hh; O1l[o] = ll;
                    }
                }
            }

    if constexpr (OM == 2) {
        // per-tile column sums: this block covers one (b, qt) x 128 d-rows
        __syncthreads();                 // all LDS frag reads done -> reuse lAh
        float* TSL = (float*)lAh;        // 256 floats
        #pragma unroll
        for (int mi = 0; mi < 4; ++mi)
            #pragma unroll
            for (int r = 0; r < 4; ++r) {
                float s = acc[mi][0][r] + acc[mi][1][r];
                s += __shfl_xor(s, 1); s += __shfl_xor(s, 2);
                s += __shfl_xor(s, 4); s += __shfl_xor(s, 8);
                if (fr == 0) TSL[wc * 128 + wr * 64 + mi * 16 + fq * 4 + r] = s;
            }
        __syncthreads();
        if (tid < 128) {
            const float ts = TSL[tid] + TSL[128 + tid];
            const int bq = bn >> 11;
            const int qt = (bn & 2047) >> 6;
            const int bhh = (bq << 4) + ((bm + tid) >> 6);
            const int dq = (bm + tid) & 63;
            TSg[((size_t)bhh * QTILES + qt) * 64 + dq] = ts;
        }
    }
}

// ---------------- suffix scan over tile sums -> STile ----------------
__global__ __launch_bounds__(64) void scan_kernel(const float* __restrict__ TSg,
                                                  float* __restrict__ STile) {
    const int bh = blockIdx.x;
    const int d = threadIdx.x;
    float s = 0.f;
    STile[((size_t)bh * 33 + 32) * 64 + d] = 0.f;
    for (int qt = QTILES - 1; qt >= 0; --qt) {
        s += TSg[((size_t)bh * QTILES + qt) * 64 + d];
        STile[((size_t)bh * 33 + qt) * 64 + d] = s;
    }
}

// ---------------- MFMA flash attention: 1 q-tile/block, K dbuf, V single-buf ----------------
// 1024 blocks = 32 bh x 32 qt; big qt dispatched first (qt = 31 - g>>5) for load balance;
// bh locked to one XCD for K/V L2 locality. 4 waves; wave w owns q-rows [w*16, w*16+16).
// Static max M=0; -U folded into y via negated causal ones MFMA on the diagonal tile;
// + STile at the end.
// QK^T computes mfma(K, Q) = S^T so each lane holds P[key=j*16+hi4*4+r][q=lx]; the
// P->A-frag transpose is done ENTIRELY IN REGISTERS with a 2-stage permlane butterfly
// (swap lane-bit5 with key-bit j0, then lane-bit4 with key-bit a1) -- no LDS round trip,
// no bank conflicts. V is single-buffered: staged after BAR1, drained (per-wave vmcnt)
// + BAR2 before PV -> race-free, and LDS drops to 48KB (3 blocks/CU).
__global__ __launch_bounds__(256, 3) void attn_kernel(const u16* __restrict__ Qh, const u16* __restrict__ Ql,
                                                      const u16* __restrict__ Kh, const u16* __restrict__ Kl,
                                                      const u16* __restrict__ Vth, const u16* __restrict__ Vtl,
                                                      const float* __restrict__ STile,
                                                      u16* __restrict__ Yh, u16* __restrict__ Yl) {
    const int g = blockIdx.x;            // 1024
    const int xcd = g & 7;
    const int bh = xcd + 8 * ((g >> 3) & 3);   // bh locked to one XCD
    const int qt = 31 - (g >> 5);              // big tiles first in dispatch order
    const int b = bh >> 4, h = bh & 15;
    const int tid = threadIdx.x;
    const int w = tid >> 6, lane = tid & 63;
    const int lx = lane & 15, hi4 = lane >> 4;

    __shared__ u16 Ksh[2 * 4096], Ksl[2 * 4096];   // 32KB: K dbuf
    __shared__ u16 Vsh[4096], Vsl[4096];           // 16KB: V single buffer

    const u16* Kgh = Kh + (size_t)b * TT * CC + h * HS;
    const u16* Kgl = Kl + (size_t)b * TT * CC + h * HS;
    const u16* Vgh = Vth + (size_t)bh * HS * TT;
    const u16* Vgl = Vtl + (size_t)bh * HS * TT;

    // staging geometry: chunk s = uu*256 + w*64 + lane; linear dest, source col pre-swizzled
    const int s0 = w * 64 + lane, s1 = 256 + w * 64 + lane;
    const int rr0 = s0 >> 3, gc0 = (s0 & 7) ^ (rr0 & 7);
    const int rr1 = s1 >> 3, gc1 = (s1 & 7) ^ (rr1 & 7);
    const int db0 = (w * 64) * 8, db1 = (256 + w * 64) * 8;
    const size_t kbase0 = (size_t)rr0 * CC + gc0 * 8;
    const size_t kbase1 = (size_t)rr1 * CC + gc1 * 8;
    const size_t vbase0 = (size_t)rr0 * TT + gc0 * 8;
    const size_t vbase1 = (size_t)rr1 * TT + gc1 * 8;

    auto stage_K = [&](int kt, int buf) {
        const size_t ko = (size_t)kt * 64 * CC;
        const int bo = buf * 4096;
        glds16(Kgh + ko + kbase0, Ksh + bo + db0);
        glds16(Kgh + ko + kbase1, Ksh + bo + db1);
        glds16(Kgl + ko + kbase0, Ksl + bo + db0);
        glds16(Kgl + ko + kbase1, Ksl + bo + db1);
    };
    auto stage_V = [&](int kt) {
        const int vo = kt * 64;
        glds16(Vgh + vbase0 + vo, Vsh + db0);
        glds16(Vgh + vbase1 + vo, Vsh + db1);
        glds16(Vgl + vbase0 + vo, Vsl + db0);
        glds16(Vgl + vbase1 + vo, Vsl + db1);
    };

    // NEGATED causal-inclusive ones A-frags (fold -U into y on the diagonal tile)
    short8v nones[2];
    #pragma unroll
    for (int k0 = 0; k0 < 2; ++k0)
        #pragma unroll
        for (int jj = 0; jj < 8; ++jj)
            nones[k0][jj] = (short)(((k0 * 32 + hi4 * 8 + jj) <= (w * 16 + lx)) ? 0xBF80 : 0);

    int cur = 0;
    stage_K(0, 0);

    const size_t qoff = (size_t)(b * TT + qt * 64 + w * 16 + lx) * CC + h * HS + hi4 * 8;
    short8v qfh[2], qfl[2];
    qfh[0] = *(const short8v*)(Qh + qoff); qfh[1] = *(const short8v*)(Qh + qoff + 32);
    qfl[0] = *(const short8v*)(Ql + qoff); qfl[1] = *(const short8v*)(Ql + qoff + 32);

    const f32x4 zero = {0.f, 0.f, 0.f, 0.f};
    f32x4 y4[4];
    float lsum = 0.f;
    #pragma unroll
    for (int dt = 0; dt < 4; ++dt) y4[dt] = zero;

    for (int kt = 0; kt <= qt; ++kt) {
        BAR();   // BAR1: prev iter's PV readers of Vs done -> stage_V may overwrite
        stage_V(kt);
        if (kt < qt) { stage_K(kt + 1, cur ^ 1); WAITV(8); }  // drain K(kt); keep {V(kt),K(kt+1)}
        else         { WAITV(4); }                            // drain K(kt); keep V(kt)

        const int co = cur * 512;
        const bool diag = (kt == qt);

        // ---- QK^T (swapped: A=K, B=Q -> D = S^T) ----
        f32x4 s4[4];
        #pragma unroll
        for (int j = 0; j < 4; ++j) s4[j] = zero;
        __builtin_amdgcn_s_setprio(1);
        #pragma unroll
        for (int j = 0; j < 4; ++j) {
            const int keyr = j * 16 + lx;
            const int rb = keyr * 8, sw = keyr & 7;
            #pragma unroll
            for (int d0 = 0; d0 < 2; ++d0) {
                const int sl = co + rb + ((hi4 + 4 * d0) ^ sw);
                const short8v kbh = ((const short8v*)Ksh)[sl];
                const short8v kbl = ((const short8v*)Ksl)[sl];
                s4[j] = __builtin_amdgcn_mfma_f32_16x16x32_bf16(kbh, qfh[d0], s4[j], 0, 0, 0);
                s4[j] = __builtin_amdgcn_mfma_f32_16x16x32_bf16(kbh, qfl[d0], s4[j], 0, 0, 0);
                s4[j] = __builtin_amdgcn_mfma_f32_16x16x32_bf16(kbl, qfh[d0], s4[j], 0, 0, 0);
            }
        }
        __builtin_amdgcn_s_setprio(0);

        // ---- softmax (static M=0): lane holds P[key=j*16+hi4*4+r][q=lx] ----
        // Wq pre-scaled by log2e -> single v_exp_f32; masked-0 quirk handled by -U fold.
        unsigned Wh[4][2], Wl[4][2];   // [j][h]: bf16 pair of keys {.., ..}
        #pragma unroll
        for (int j = 0; j < 4; ++j) {
            float pv[4];
            #pragma unroll
            for (int r = 0; r < 4; ++r) {
                float e = __builtin_amdgcn_exp2f(s4[j][r]);
                if (diag && (j * 16 + hi4 * 4 + r) > (w * 16 + lx)) e = 0.f;
                lsum += e;
                pv[r] = e;
            }
            const u16 p0 = f2bf(pv[0]), p1 = f2bf(pv[1]), p2 = f2bf(pv[2]), p3 = f2bf(pv[3]);
            Wh[j][0] = (unsigned)p0 | ((unsigned)p1 << 16);
            Wh[j][1] = (unsigned)p2 | ((unsigned)p3 << 16);
            Wl[j][0] = (unsigned)f2bf(pv[0] - bf2f(p0)) | ((unsigned)f2bf(pv[1] - bf2f(p1)) << 16);
            Wl[j][1] = (unsigned)f2bf(pv[2] - bf2f(p2)) | ((unsigned)f2bf(pv[3] - bf2f(p3)) << 16);
        }
        // ---- in-register P transpose: 2-stage permlane butterfly ----
        // word(j,h) at lane (a1,a0) -> slot (k0=j>>1, i=2*a0+h) at lane (j&1, a1).
        // stage1 (lanes +-32): lane-bit1 <-> j0; stage2 (lanes +-16): lane-bit0 <-> a1.
        #pragma unroll
        for (int j1 = 0; j1 < 2; ++j1)
            #pragma unroll
            for (int hh = 0; hh < 2; ++hh) {
                swap32(Wh[2 * j1][hh], Wh[2 * j1 + 1][hh]);
                swap16(Wh[2 * j1][hh], Wh[2 * j1 + 1][hh]);
                swap32(Wl[2 * j1][hh], Wl[2 * j1 + 1][hh]);
                swap16(Wl[2 * j1][hh], Wl[2 * j1 + 1][hh]);
            }
        short8v pah[2], pal[2];
        #pragma unroll
        for (int k0 = 0; k0 < 2; ++k0) {
            u32x4 ah = {Wh[2 * k0][0], Wh[2 * k0][1], Wh[2 * k0 + 1][0], Wh[2 * k0 + 1][1]};
            u32x4 al = {Wl[2 * k0][0], Wl[2 * k0][1], Wl[2 * k0 + 1][0], Wl[2 * k0 + 1][1]};
            pah[k0] = __builtin_bit_cast(short8v, ah);
            pal[k0] = __builtin_bit_cast(short8v, al);
        }

        if (kt < qt) { WAITV(4); }   // drain V(kt); keep K(kt+1) in flight
        else         { WAITV(0); }
        BAR();   // BAR2: all waves' V(kt) DMA landed -> Vs complete

        // ---- PV (+ negated causal-ones on the diagonal tile) ----
        __builtin_amdgcn_s_setprio(1);
        #pragma unroll
        for (int dt = 0; dt < 4; ++dt) {
            const int drow = dt * 16 + lx;
            const int rb = drow * 8, sw = drow & 7;
            #pragma unroll
            for (int k0 = 0; k0 < 2; ++k0) {
                const int sl = rb + ((hi4 + 4 * k0) ^ sw);
                const short8v vbh = ((const short8v*)Vsh)[sl];
                const short8v vbl = ((const short8v*)Vsl)[sl];
                y4[dt] = __builtin_amdgcn_mfma_f32_16x16x32_bf16(pah[k0], vbh, y4[dt], 0, 0, 0);
                y4[dt] = __builtin_amdgcn_mfma_f32_16x16x32_bf16(pal[k0], vbh, y4[dt], 0, 0, 0);
                y4[dt] = __builtin_amdgcn_mfma_f32_16x16x32_bf16(pah[k0], vbl, y4[dt], 0, 0, 0);
                if (diag) {
                    y4[dt] = __builtin_amdgcn_mfma_f32_16x16x32_bf16(nones[k0], vbh, y4[dt], 0, 0, 0);
                    y4[dt] = __builtin_amdgcn_mfma_f32_16x16x32_bf16(nones[k0], vbl, y4[dt], 0, 0, 0);
                }
            }
        }
        __builtin_amdgcn_s_setprio(0);

        cur ^= 1;
    }

    // ---- l reduce: lsum is per-lane (q=lx); sum hi4 groups, redistribute to (hi4,r) ----
    lsum += __shfl_xor(lsum, 16);
    lsum += __shfl_xor(lsum, 32);
    float l4[4];
    #pragma unroll
    for (int r = 0; r < 4; ++r) l4[r] = __shfl(lsum, hi4 * 4 + r);

    // ---- masked-zero tail: y holds (PV - U); add STile, normalize ----
    const float* stp = STile + ((size_t)bh * 33 + qt) * 64;
    #pragma unroll
    for (int dt = 0; dt < 4; ++dt) {
        const float st = stp[dt * 16 + lx];
        #pragma unroll
        for (int r = 0; r < 4; ++r) {
            const int t = qt * 64 + w * 16 + hi4 * 4 + r;
            const float linv = 1.f / (l4[r] + (float)(TT - 1 - t));
            const float yv = (y4[dt][r] + st) * linv;
            const u16 hh = f2bf(yv);
            const u16 l2 = f2bf(yv - bf2f(hh));
            const size_t off = (size_t)(b * TT + t) * CC + h * HS + dt * 16 + lx;
            Yh[off] = hh; Yl[off] = l2;
        }
    }
}

// ---------------- launch ----------------
extern "C" void kernel_launch(void* const* d_in, const int* in_sizes, int n_in,
                              void* d_out, int out_size, void* d_ws, size_t ws_size,
                              hipStream_t stream) {
    const float* x  = (const float*)d_in[0];
    const float* Wq = (const float*)d_in[1];
    const float* Wk = (const float*)d_in[2];
    const float* Wv = (const float*)d_in[3];
    const float* Wp = (const float*)d_in[4];
    float* out = (float*)d_out;

    const size_t NC = (size_t)NROWS * CC;       // 4M elements
    const size_t WC = (size_t)CC * CC;          // 1M elements
    char* ws = (char*)d_ws;
    // [0,16MB): x splits; after Vt-GEMM x is dead -> Y splits
    u16* xh = (u16*)ws;                  u16* xl = xh + NC;
    u16* Yh = xh;                        u16* Yl = xl;
    // [16,32MB): Q splits
    u16* Qh = (u16*)(ws + (16u << 20));  u16* Ql = Qh + NC;
    // [32,48MB): K splits
    u16* Kh = (u16*)(ws + (32u << 20));  u16* Kl = Kh + NC;
    // [48,52MB): Wv splits (dead after Vt GEMM); [52,52.25MB): TSg (dead after scan)
    u16* wvh = (u16*)(ws + (48u << 20)); u16* wvl = wvh + WC;
    float* TSg = (float*)(ws + (52u << 20));   // 32*32*64 floats = 256KB
    // [56,64MB): Wp splits
    u16* wph = (u16*)(ws + (56u << 20)); u16* wpl = wph + WC;
    // [64MB,+270KB): STile
    float* St = (float*)(ws + (64u << 20));
    // d_out (16MB): first wqk splits, then Vt splits, finally the real output
    u16* wqk = (u16*)out;
    u16* Vth = (u16*)out;                u16* Vtl = Vth + NC;

    fsplit_kernel<<<8192, 256, 0, stream>>>(x, Wq, Wk, Wv, Wp, xh, xl, wqk, wvh, wvl, wph, wpl);

    // fused Q+K GEMM: N=2048, 128x128 tiles -> 512 blocks
    gemm_mfma<128, 1><<<dim3(2048 / 128, NROWS / 128), 256, 0, stream>>>(
        xh, xl, wqk, wqk + 2 * WC, nullptr, Qh, Ql, Kh, Kl, nullptr, NROWS, 2048, CC);

    // V^T GEMM: A=Wv (M=1024), B=x (N=4096) -> Vt splits in d_out + per-tile colsums
    gemm_mfma<64, 2><<<dim3(NROWS / 64, CC / 128), 256, 0, stream>>>(
        wvh, wvl, xh, xl, nullptr, Vth, Vtl, nullptr, nullptr, TSg, CC, NROWS, CC);

    scan_kernel<<<BB * HH, 64, 0, stream>>>(TSg, St);

    attn_kernel<<<1024, 256, 0, stream>>>(Qh, Ql, Kh, Kl, Vth, Vtl, St, Yh, Yl);

    // output projection (overwrites d_out; Vt is dead)
    gemm_mfma<64, 0><<<dim3(CC / 64, NROWS / 128), 256, 0, stream>>>(
        Yh, Yl, wph, wpl, out, nullptr, nullptr, nullptr, nullptr, nullptr, NROWS, CC, CC);
}

// Round 3
// 115.490 us; speedup vs baseline: 1.8447x; 1.7728x over previous
//
#include <hip/hip_runtime.h>
#include <hip/hip_bf16.h>
#include <math.h>

#define BB 2
#define TT 2048
#define CC 1024
#define HH 16
#define HS 64
#define NROWS (BB * TT)   // 4096
#define QTILES (TT / 64)  // 32

typedef __attribute__((ext_vector_type(8))) short short8v;   // 8 bf16 (4 VGPRs)
typedef __attribute__((ext_vector_type(4))) float f32x4;
typedef __attribute__((ext_vector_type(4))) unsigned int u32x4;
typedef unsigned short u16;

__device__ __forceinline__ u16 f2bf(float f) {
    return __builtin_bit_cast(u16, (__bf16)f);   // RNE hw cvt
}

// async global->LDS, 16B/lane; LDS dest = wave-uniform base + lane*16
__device__ __forceinline__ void glds16(const void* g, void* l) {
    __builtin_amdgcn_global_load_lds((__attribute__((address_space(1))) void*)g,
                                     (__attribute__((address_space(3))) void*)l, 16, 0, 0);
}
#define WAITV(N) asm volatile("s_waitcnt vmcnt(" #N ")" ::: "memory")
#define BAR() do { __builtin_amdgcn_s_barrier(); __builtin_amdgcn_sched_barrier(0); } while (0)

// cross-lane half-swaps (gfx950): after swap32(a,b): a = {a.lo32, b.lo32}, b = {a.hi32, b.hi32}
__device__ __forceinline__ void swap32(unsigned& a, unsigned& b) {
    asm volatile("v_permlane32_swap_b32 %0, %1" : "+v"(a), "+v"(b));
}
__device__ __forceinline__ void swap16(unsigned& a, unsigned& b) {
    asm volatile("v_permlane16_swap_b32 %0, %1" : "+v"(a), "+v"(b));
}

// ---------------- fused cast: x + all 4 weight matrices -> bf16 (one launch) ----------------
__global__ __launch_bounds__(256) void fsplit_kernel(const float* __restrict__ x,
                                                     const float* __restrict__ Wq, const float* __restrict__ Wk,
                                                     const float* __restrict__ Wv, const float* __restrict__ Wp,
                                                     u16* __restrict__ xh,
                                                     u16* __restrict__ wqk,   // d_out: [Wq_h|Wk_h]
                                                     u16* __restrict__ wv, u16* __restrict__ wp) {
    const size_t WC = (size_t)CC * CC;
    const int bid = blockIdx.x;
    const float* src; u16* dh; float sc = 1.f; int i;
    if (bid < 4096) {            // x: 4M elements / 4 per thread
        src = x; dh = xh; i = bid * 256 + threadIdx.x;
    } else {
        const int wsel = (bid - 4096) >> 10;
        i = ((bid - 4096) & 1023) * 256 + threadIdx.x;
        // fold 1/8 AND log2(e) into Wq: attn softmax then uses a single v_exp_f32 (exp2)
        if (wsel == 0)      { src = Wq; dh = wqk;      sc = 0.125f * 1.4426950408889634f; }
        else if (wsel == 1) { src = Wk; dh = wqk + WC; }
        else if (wsel == 2) { src = Wv; dh = wv; }
        else                { src = Wp; dh = wp; }
    }
    float4 v = ((const float4*)src)[i];
    v.x *= sc; v.y *= sc; v.z *= sc; v.w *= sc;
    ushort4 H;
    H.x = f2bf(v.x); H.y = f2bf(v.y); H.z = f2bf(v.z); H.w = f2bf(v.w);
    ((ushort4*)dh)[i] = H;
}

// ---------------- bf16 MFMA GEMM, pipelined (1 bar/step, counted vmcnt) ----------------
// OM=0: fp32 out (stride N). OM=1: bf16 out, col<CC -> O1 else O2 (stride CC).
// OM=2: transposed V^T epilogue -> O1 = Vt[bh][d][t] bf16 + per-tile colsum TSg.
template<int GNT, int OM>
__global__ __launch_bounds__(256) void gemm_mfma(const u16* __restrict__ A, const u16* __restrict__ B,
                                                 float* __restrict__ O,
                                                 u16* __restrict__ O1, u16* __restrict__ O2,
                                                 float* __restrict__ TSg,
                                                 int M, int N, int K) {
    constexpr int NI = GNT / 32;                   // B frags per wave
    constexpr int BCH = (GNT == 128) ? 512 : 256;  // B buffer chunk count
    __shared__ u16 lA[2 * 4096], lB[2 * GNT * 32];
    const int tid = threadIdx.x;
    const int lane = tid & 63, w = tid >> 6;
    const int wr = w >> 1, wc = w & 1;
    const int fr = lane & 15, fc = lane >> 4;

    const int nbx = gridDim.x;
    const int bid = blockIdx.y * nbx + blockIdx.x;
    const int nwg = nbx * gridDim.y;
    const int swz = (bid & 7) * (nwg >> 3) + (bid >> 3);
    const int bm = (swz / nbx) * 128, bn = (swz % nbx) * GNT;

    f32x4 acc[4][NI];
    #pragma unroll
    for (int i = 0; i < 4; ++i)
        #pragma unroll
        for (int j = 0; j < NI; ++j) acc[i][j] = (f32x4){0.f, 0.f, 0.f, 0.f};

    const int lrow = lane >> 2, lcs = lane & 3;
    const int rA0 = w * 16 + lrow, rA1 = rA0 + 64;
    const size_t aoff0 = (size_t)(bm + rA0) * K + (lcs ^ ((rA0 >> 1) & 3)) * 8;
    const size_t aoff1 = (size_t)(bm + rA1) * K + (lcs ^ ((rA1 >> 1) & 3)) * 8;
    const size_t boff0 = (size_t)(bn + rA0) * K + (lcs ^ ((rA0 >> 1) & 3)) * 8;
    size_t boff1 = 0;
    if constexpr (GNT == 128) boff1 = (size_t)(bn + rA1) * K + (lcs ^ ((rA1 >> 1) & 3)) * 8;
    const int d0 = w * 512, d1 = 2048 + w * 512;

    int aslot[4], bslot[NI];
    #pragma unroll
    for (int mi = 0; mi < 4; ++mi) {
        int row = wr * 64 + mi * 16 + fr;
        aslot[mi] = row * 4 + (fc ^ ((row >> 1) & 3));
    }
    #pragma unroll
    for (int ni = 0; ni < NI; ++ni) {
        int col = wc * (GNT / 2) + ni * 16 + fr;
        bslot[ni] = col * 4 + (fc ^ ((col >> 1) & 3));
    }

    auto STAGE = [&](int t, int buf) {
        const int k0 = t * 32;
        const int bo = buf * 4096;
        glds16(A + aoff0 + k0, lA + bo + d0);
        glds16(A + aoff1 + k0, lA + bo + d1);
        if constexpr (GNT == 128) {
            glds16(B + boff0 + k0, lB + bo + d0);
            glds16(B + boff1 + k0, lB + bo + d1);
        } else {
            const int bo2 = buf * 2048;
            glds16(B + boff0 + k0, lB + bo2 + d0);
        }
    };

    const int nt = K >> 5;
    STAGE(0, 0);

    #pragma unroll 2
    for (int t = 0; t < nt; ++t) {
        const int cur = t & 1;
        BAR();   // prev iter's readers of buf[cur^1] are done -> safe to overwrite
        if (t + 1 < nt) {
            STAGE(t + 1, cur ^ 1);
            if constexpr (GNT == 128) { WAITV(4); } else { WAITV(3); }  // tile t landed
        } else {
            WAITV(0);
        }

        const int co = cur * 512, co2 = cur * BCH;
        short8v fa[4], fb[NI];
        #pragma unroll
        for (int mi = 0; mi < 4; ++mi) fa[mi] = ((const short8v*)lA)[co + aslot[mi]];
        #pragma unroll
        for (int ni = 0; ni < NI; ++ni) fb[ni] = ((const short8v*)lB)[co2 + bslot[ni]];
        __builtin_amdgcn_s_setprio(1);
        #pragma unroll
        for (int mi = 0; mi < 4; ++mi)
            #pragma unroll
            for (int ni = 0; ni < NI; ++ni)
                acc[mi][ni] = __builtin_amdgcn_mfma_f32_16x16x32_bf16(fa[mi], fb[ni], acc[mi][ni], 0, 0, 0);
        __builtin_amdgcn_s_setprio(0);
    }

    const int fq = lane >> 4;
    #pragma unroll
    for (int mi = 0; mi < 4; ++mi)
        #pragma unroll
        for (int ni = 0; ni < NI; ++ni)
            #pragma unroll
            for (int r = 0; r < 4; ++r) {
                const int rg = bm + wr * 64 + mi * 16 + fq * 4 + r;
                const int cg = bn + wc * (GNT / 2) + ni * 16 + fr;
                const float v = acc[mi][ni][r];
                if constexpr (OM == 0) {
                    O[(size_t)rg * N + cg] = v;
                } else if constexpr (OM == 1) {
                    const u16 hh = f2bf(v);
                    if (cg < CC) O1[(size_t)rg * CC + cg] = hh;
                    else         O2[(size_t)rg * CC + cg - CC] = hh;
                } else {  // OM == 2: O1 = V^T; rg = h*64+d, cg = b*2048+t
                    const int bq = cg >> 11, tq = cg & 2047;
                    const int hq = rg >> 6, dq = rg & 63;
                    O1[((size_t)((bq << 4) + hq) * HS + dq) * TT + tq] = f2bf(v);
                }
            }

    if constexpr (OM == 2) {
        // per-tile column sums: this block covers one (b, qt) x 128 d-rows
        __syncthreads();                 // all LDS frag reads done -> reuse lA
        float* TSL = (float*)lA;         // 256 floats
        #pragma unroll
        for (int mi = 0; mi < 4; ++mi)
            #pragma unroll
            for (int r = 0; r < 4; ++r) {
                float s = acc[mi][0][r] + acc[mi][1][r];
                s += __shfl_xor(s, 1); s += __shfl_xor(s, 2);
                s += __shfl_xor(s, 4); s += __shfl_xor(s, 8);
                if (fr == 0) TSL[wc * 128 + wr * 64 + mi * 16 + fq * 4 + r] = s;
            }
        __syncthreads();
        if (tid < 128) {
            const float ts = TSL[tid] + TSL[128 + tid];
            const int bq = bn >> 11;
            const int qt = (bn & 2047) >> 6;
            const int bhh = (bq << 4) + ((bm + tid) >> 6);
            const int dq = (bm + tid) & 63;
            TSg[((size_t)bhh * QTILES + qt) * 64 + dq] = ts;
        }
    }
}

// ---------------- suffix scan over tile sums -> STile ----------------
__global__ __launch_bounds__(64) void scan_kernel(const float* __restrict__ TSg,
                                                  float* __restrict__ STile) {
    const int bh = blockIdx.x;
    const int d = threadIdx.x;
    float s = 0.f;
    STile[((size_t)bh * 33 + 32) * 64 + d] = 0.f;
    for (int qt = QTILES - 1; qt >= 0; --qt) {
        s += TSg[((size_t)bh * QTILES + qt) * 64 + d];
        STile[((size_t)bh * 33 + qt) * 64 + d] = s;
    }
}

// ---------------- MFMA flash attention, pure bf16: 1 q-tile/block, K dbuf, V single-buf ----------------
// 1024 blocks = 32 bh x 32 qt; big qt dispatched first; bh locked to one XCD.
// 4 waves; wave w owns q-rows [w*16, w*16+16). Static max M=0; -U folded into y via
// negated causal ones MFMA on the diagonal tile; + STile at the end.
// QK^T computes mfma(K, Q) = S^T so each lane holds P[key=j*16+hi4*4+r][q=lx]; the
// P->A-frag transpose is a 2-stage permlane butterfly, fully in-register.
// Sync per kt: {WAITV(0); BAR} makes everyone's K(kt) DMA visible BEFORE the QK reads
// (race-free by construction); V staged at top, drained + BAR'd before PV.
__global__ __launch_bounds__(256, 4) void attn_kernel(const u16* __restrict__ Qh,
                                                      const u16* __restrict__ Kh,
                                                      const u16* __restrict__ Vt,
                                                      const float* __restrict__ STile,
                                                      u16* __restrict__ Yh) {
    const int g = blockIdx.x;            // 1024
    const int bh = (g & 7) + 8 * ((g >> 3) & 3);   // bh locked to one XCD
    const int qt = 31 - (g >> 5);                  // big tiles first in dispatch order
    const int b = bh >> 4, h = bh & 15;
    const int tid = threadIdx.x;
    const int w = tid >> 6, lane = tid & 63;
    const int lx = lane & 15, hi4 = lane >> 4;

    __shared__ u16 Ksh[2 * 4096];   // 16KB: K dbuf
    __shared__ u16 Vsh[4096];       // 8KB: V single buffer

    const u16* Kg = Kh + (size_t)b * TT * CC + h * HS;
    const u16* Vg = Vt + (size_t)bh * HS * TT;

    // staging geometry: chunk s = w*64 + lane (+256); linear dest, source col pre-swizzled
    const int s0 = w * 64 + lane, s1 = 256 + w * 64 + lane;
    const int rr0 = s0 >> 3, gc0 = (s0 & 7) ^ (rr0 & 7);
    const int rr1 = s1 >> 3, gc1 = (s1 & 7) ^ (rr1 & 7);
    const int db0 = (w * 64) * 8, db1 = (256 + w * 64) * 8;
    const size_t kbase0 = (size_t)rr0 * CC + gc0 * 8;
    const size_t kbase1 = (size_t)rr1 * CC + gc1 * 8;
    const size_t vbase0 = (size_t)rr0 * TT + gc0 * 8;
    const size_t vbase1 = (size_t)rr1 * TT + gc1 * 8;

    auto stage_K = [&](int kt, int buf) {
        const size_t ko = (size_t)kt * 64 * CC;
        const int bo = buf * 4096;
        glds16(Kg + ko + kbase0, Ksh + bo + db0);
        glds16(Kg + ko + kbase1, Ksh + bo + db1);
    };
    auto stage_V = [&](int kt) {
        const int vo = kt * 64;
        glds16(Vg + vbase0 + vo, Vsh + db0);
        glds16(Vg + vbase1 + vo, Vsh + db1);
    };

    // NEGATED causal-inclusive ones A-frags (fold -U into y on the diagonal tile)
    short8v nones[2];
    #pragma unroll
    for (int k0 = 0; k0 < 2; ++k0)
        #pragma unroll
        for (int jj = 0; jj < 8; ++jj)
            nones[k0][jj] = (short)(((k0 * 32 + hi4 * 8 + jj) <= (w * 16 + lx)) ? 0xBF80 : 0);

    int cur = 0;
    stage_K(0, 0);

    const size_t qoff = (size_t)(b * TT + qt * 64 + w * 16 + lx) * CC + h * HS + hi4 * 8;
    short8v qf[2];
    qf[0] = *(const short8v*)(Qh + qoff); qf[1] = *(const short8v*)(Qh + qoff + 32);

    const f32x4 zero = {0.f, 0.f, 0.f, 0.f};
    f32x4 y4[4];
    float lsum = 0.f;
    #pragma unroll
    for (int dt = 0; dt < 4; ++dt) y4[dt] = zero;

    for (int kt = 0; kt <= qt; ++kt) {
        WAITV(0);   // own K(kt) (and V(kt-1)) drained -> landed
        BAR();      // everyone's K(kt) visible; prev PV readers of Vsh done
        stage_V(kt);
        if (kt < qt) stage_K(kt + 1, cur ^ 1);

        const int co = cur * 512;
        const bool diag = (kt == qt);

        // ---- QK^T (swapped: A=K, B=Q -> D = S^T) ----
        f32x4 s4[4];
        #pragma unroll
        for (int j = 0; j < 4; ++j) s4[j] = zero;
        __builtin_amdgcn_s_setprio(1);
        #pragma unroll
        for (int j = 0; j < 4; ++j) {
            const int keyr = j * 16 + lx;
            const int rb = keyr * 8, sw = keyr & 7;
            #pragma unroll
            for (int d0 = 0; d0 < 2; ++d0) {
                const short8v kb = ((const short8v*)Ksh)[co + rb + ((hi4 + 4 * d0) ^ sw)];
                s4[j] = __builtin_amdgcn_mfma_f32_16x16x32_bf16(kb, qf[d0], s4[j], 0, 0, 0);
            }
        }
        __builtin_amdgcn_s_setprio(0);

        // ---- softmax (static M=0): lane holds P[key=j*16+hi4*4+r][q=lx] ----
        unsigned Wp[4][2];   // [j][h]: bf16 pair of adjacent keys
        #pragma unroll
        for (int j = 0; j < 4; ++j) {
            float pv[4];
            #pragma unroll
            for (int r = 0; r < 4; ++r) {
                float e = __builtin_amdgcn_exp2f(s4[j][r]);
                if (diag && (j * 16 + hi4 * 4 + r) > (w * 16 + lx)) e = 0.f;
                lsum += e;
                pv[r] = e;
            }
            Wp[j][0] = (unsigned)f2bf(pv[0]) | ((unsigned)f2bf(pv[1]) << 16);
            Wp[j][1] = (unsigned)f2bf(pv[2]) | ((unsigned)f2bf(pv[3]) << 16);
        }
        // ---- in-register P transpose: 2-stage permlane butterfly ----
        #pragma unroll
        for (int j1 = 0; j1 < 2; ++j1)
            #pragma unroll
            for (int hh = 0; hh < 2; ++hh) {
                swap32(Wp[2 * j1][hh], Wp[2 * j1 + 1][hh]);
                swap16(Wp[2 * j1][hh], Wp[2 * j1 + 1][hh]);
            }
        short8v pa[2];
        #pragma unroll
        for (int k0 = 0; k0 < 2; ++k0) {
            u32x4 ah = {Wp[2 * k0][0], Wp[2 * k0][1], Wp[2 * k0 + 1][0], Wp[2 * k0 + 1][1]};
            pa[k0] = __builtin_bit_cast(short8v, ah);
        }

        if (kt < qt) { WAITV(2); }   // drain V(kt); keep K(kt+1) in flight
        else         { WAITV(0); }
        BAR();   // everyone's V(kt) DMA landed -> Vsh complete

        // ---- PV (+ negated causal-ones on the diagonal tile) ----
        __builtin_amdgcn_s_setprio(1);
        #pragma unroll
        for (int dt = 0; dt < 4; ++dt) {
            const int drow = dt * 16 + lx;
            const int rb = drow * 8, sw = drow & 7;
            #pragma unroll
            for (int k0 = 0; k0 < 2; ++k0) {
                const short8v vb = ((const short8v*)Vsh)[rb + ((hi4 + 4 * k0) ^ sw)];
                y4[dt] = __builtin_amdgcn_mfma_f32_16x16x32_bf16(pa[k0], vb, y4[dt], 0, 0, 0);
                if (diag)
                    y4[dt] = __builtin_amdgcn_mfma_f32_16x16x32_bf16(nones[k0], vb, y4[dt], 0, 0, 0);
            }
        }
        __builtin_amdgcn_s_setprio(0);

        cur ^= 1;
    }

    // ---- l reduce: lsum is per-lane (q=lx); sum hi4 groups, redistribute to (hi4,r) ----
    lsum += __shfl_xor(lsum, 16);
    lsum += __shfl_xor(lsum, 32);
    float l4[4];
    #pragma unroll
    for (int r = 0; r < 4; ++r) l4[r] = __shfl(lsum, hi4 * 4 + r);

    // ---- masked-zero tail: y holds (PV - U); add STile, normalize ----
    const float* stp = STile + ((size_t)bh * 33 + qt) * 64;
    #pragma unroll
    for (int dt = 0; dt < 4; ++dt) {
        const float st = stp[dt * 16 + lx];
        #pragma unroll
        for (int r = 0; r < 4; ++r) {
            const int t = qt * 64 + w * 16 + hi4 * 4 + r;
            const float linv = 1.f / (l4[r] + (float)(TT - 1 - t));
            const float yv = (y4[dt][r] + st) * linv;
            const size_t off = (size_t)(b * TT + t) * CC + h * HS + dt * 16 + lx;
            Yh[off] = f2bf(yv);
        }
    }
}

// ---------------- launch ----------------
extern "C" void kernel_launch(void* const* d_in, const int* in_sizes, int n_in,
                              void* d_out, int out_size, void* d_ws, size_t ws_size,
                              hipStream_t stream) {
    const float* x  = (const float*)d_in[0];
    const float* Wq = (const float*)d_in[1];
    const float* Wk = (const float*)d_in[2];
    const float* Wv = (const float*)d_in[3];
    const float* Wp = (const float*)d_in[4];
    float* out = (float*)d_out;

    const size_t NC = (size_t)NROWS * CC;       // 4M elements
    const size_t WC = (size_t)CC * CC;          // 1M elements
    char* ws = (char*)d_ws;
    // [0,8MB): x bf16; after Vt-GEMM x is dead -> Y bf16
    u16* xh = (u16*)ws;
    u16* Yh = xh;
    // [16,24MB): Q bf16; [32,40MB): K bf16
    u16* Qh = (u16*)(ws + (16u << 20));
    u16* Kh = (u16*)(ws + (32u << 20));
    // [48,50MB): Wv bf16; [52,+256KB): TSg (dead after scan); [56,58MB): Wp bf16
    u16* wv = (u16*)(ws + (48u << 20));
    float* TSg = (float*)(ws + (52u << 20));
    u16* wp = (u16*)(ws + (56u << 20));
    // [64MB,+270KB): STile
    float* St = (float*)(ws + (64u << 20));
    // d_out (16MB): first wqk (4MB), then Vt (8MB), finally the real output
    u16* wqk = (u16*)out;
    u16* Vth = (u16*)out;

    fsplit_kernel<<<8192, 256, 0, stream>>>(x, Wq, Wk, Wv, Wp, xh, wqk, wv, wp);

    // fused Q+K GEMM: N=2048, 128x128 tiles -> 512 blocks
    gemm_mfma<128, 1><<<dim3(2048 / 128, NROWS / 128), 256, 0, stream>>>(
        xh, wqk, nullptr, Qh, Kh, nullptr, NROWS, 2048, CC);

    // V^T GEMM: A=Wv (M=1024), B=x (N=4096) -> Vt bf16 in d_out + per-tile colsums
    gemm_mfma<64, 2><<<dim3(NROWS / 64, CC / 128), 256, 0, stream>>>(
        wv, xh, nullptr, Vth, nullptr, TSg, CC, NROWS, CC);

    scan_kernel<<<BB * HH, 64, 0, stream>>>(TSg, St);

    attn_kernel<<<1024, 256, 0, stream>>>(Qh, Kh, Vth, St, Yh);

    // output projection (overwrites d_out; Vt is dead)
    gemm_mfma<64, 0><<<dim3(CC / 64, NROWS / 128), 256, 0, stream>>>(
        Yh, wp, out, nullptr, nullptr, nullptr, NROWS, CC, CC);
}

// Round 6
// 101.343 us; speedup vs baseline: 2.1022x; 1.1396x over previous
//
#include <hip/hip_runtime.h>
#include <hip/hip_bf16.h>
#include <math.h>

#define BB 2
#define TT 2048
#define CC 1024
#define HH 16
#define HS 64
#define NROWS (BB * TT)   // 4096
#define QTILES (TT / 64)  // 32

typedef __attribute__((ext_vector_type(8))) short short8v;   // 8 bf16 (4 VGPRs)
typedef __attribute__((ext_vector_type(4))) float f32x4;
typedef __attribute__((ext_vector_type(4))) unsigned int u32x4;
typedef unsigned short u16;

__device__ __forceinline__ u16 f2bf(float f) {
    return __builtin_bit_cast(u16, (__bf16)f);   // RNE hw cvt
}

// async global->LDS, 16B/lane; LDS dest = wave-uniform base + lane*16
__device__ __forceinline__ void glds16(const void* g, void* l) {
    __builtin_amdgcn_global_load_lds((__attribute__((address_space(1))) void*)g,
                                     (__attribute__((address_space(3))) void*)l, 16, 0, 0);
}
#define WAITV(N) asm volatile("s_waitcnt vmcnt(" #N ")" ::: "memory")
#define BAR() do { __builtin_amdgcn_s_barrier(); __builtin_amdgcn_sched_barrier(0); } while (0)

// cross-lane half-swaps (gfx950): after swap32(a,b): a = {a.lo32, b.lo32}, b = {a.hi32, b.hi32}
__device__ __forceinline__ void swap32(unsigned& a, unsigned& b) {
    asm volatile("v_permlane32_swap_b32 %0, %1" : "+v"(a), "+v"(b));
}
__device__ __forceinline__ void swap16(unsigned& a, unsigned& b) {
    asm volatile("v_permlane16_swap_b32 %0, %1" : "+v"(a), "+v"(b));
}

// ---------------- fused cast: x + all 4 weight matrices -> bf16 (one launch) ----------------
__global__ __launch_bounds__(256) void fsplit_kernel(const float* __restrict__ x,
                                                     const float* __restrict__ Wq, const float* __restrict__ Wk,
                                                     const float* __restrict__ Wv, const float* __restrict__ Wp,
                                                     u16* __restrict__ xh,
                                                     u16* __restrict__ wqk,   // d_out: [Wq_h|Wk_h]
                                                     u16* __restrict__ wv, u16* __restrict__ wp) {
    const size_t WC = (size_t)CC * CC;
    const int bid = blockIdx.x;
    const float* src; u16* dh; float sc = 1.f; int i;
    if (bid < 4096) {            // x: 4M elements / 4 per thread
        src = x; dh = xh; i = bid * 256 + threadIdx.x;
    } else {
        const int wsel = (bid - 4096) >> 10;
        i = ((bid - 4096) & 1023) * 256 + threadIdx.x;
        // fold 1/8 AND log2(e) into Wq: attn softmax then uses a single v_exp_f32 (exp2)
        if (wsel == 0)      { src = Wq; dh = wqk;      sc = 0.125f * 1.4426950408889634f; }
        else if (wsel == 1) { src = Wk; dh = wqk + WC; }
        else if (wsel == 2) { src = Wv; dh = wv; }
        else                { src = Wp; dh = wp; }
    }
    float4 v = ((const float4*)src)[i];
    v.x *= sc; v.y *= sc; v.z *= sc; v.w *= sc;
    ushort4 H;
    H.x = f2bf(v.x); H.y = f2bf(v.y); H.z = f2bf(v.z); H.w = f2bf(v.w);
    ((ushort4*)dh)[i] = H;
}

// ---------------- merged QK + V^T GEMM (one launch, 768 equal 128x128 blocks) ----------------
// bid < 512:  QK GEMM  A=xh [4096xK], B=wqk [2048xK] -> Qh/Kh bf16 (stride CC)
// bid >= 512: V^T GEMM A=wv [1024xK], B=xh  [4096xK] -> Vt[bh][d][t] bf16 + colsum TSg
__global__ __launch_bounds__(256) void qkv_kernel(const u16* __restrict__ xh, const u16* __restrict__ wqk,
                                                  const u16* __restrict__ wv,
                                                  u16* __restrict__ Qo, u16* __restrict__ Ko,
                                                  u16* __restrict__ VtO, float* __restrict__ TSg) {
    __shared__ u16 lA[2 * 4096], lB[2 * 4096];
    const int tid = threadIdx.x;
    const int lane = tid & 63, w = tid >> 6;
    const int wr = w >> 1, wc = w & 1;
    const int fr = lane & 15, fc = lane >> 4;
    const int K = CC;

    const int gbid = blockIdx.x;
    const bool isQK = gbid < 512;
    const int sub = isQK ? gbid : gbid - 512;
    const int nbx = isQK ? 16 : 32;
    const int nwg = isQK ? 512 : 256;
    const u16* __restrict__ A = isQK ? xh : wv;
    const u16* __restrict__ B = isQK ? wqk : xh;

    const int swz = (sub & 7) * (nwg >> 3) + (sub >> 3);
    const int bm = (swz / nbx) * 128, bn = (swz % nbx) * 128;

    f32x4 acc[4][4];
    #pragma unroll
    for (int i = 0; i < 4; ++i)
        #pragma unroll
        for (int j = 0; j < 4; ++j) acc[i][j] = (f32x4){0.f, 0.f, 0.f, 0.f};

    const int lrow = lane >> 2, lcs = lane & 3;
    const int rA0 = w * 16 + lrow, rA1 = rA0 + 64;
    const size_t aoff0 = (size_t)(bm + rA0) * K + (lcs ^ ((rA0 >> 1) & 3)) * 8;
    const size_t aoff1 = (size_t)(bm + rA1) * K + (lcs ^ ((rA1 >> 1) & 3)) * 8;
    const size_t boff0 = (size_t)(bn + rA0) * K + (lcs ^ ((rA0 >> 1) & 3)) * 8;
    const size_t boff1 = (size_t)(bn + rA1) * K + (lcs ^ ((rA1 >> 1) & 3)) * 8;
    const int d0 = w * 512, d1 = 2048 + w * 512;

    int aslot[4], bslot[4];
    #pragma unroll
    for (int mi = 0; mi < 4; ++mi) {
        int row = wr * 64 + mi * 16 + fr;
        aslot[mi] = row * 4 + (fc ^ ((row >> 1) & 3));
    }
    #pragma unroll
    for (int ni = 0; ni < 4; ++ni) {
        int col = wc * 64 + ni * 16 + fr;
        bslot[ni] = col * 4 + (fc ^ ((col >> 1) & 3));
    }

    auto STAGE = [&](int t, int buf) {
        const int k0 = t * 32;
        const int bo = buf * 4096;
        glds16(A + aoff0 + k0, lA + bo + d0);
        glds16(A + aoff1 + k0, lA + bo + d1);
        glds16(B + boff0 + k0, lB + bo + d0);
        glds16(B + boff1 + k0, lB + bo + d1);
    };

    const int nt = K >> 5;
    STAGE(0, 0);

    #pragma unroll 2
    for (int t = 0; t < nt; ++t) {
        const int cur = t & 1;
        BAR();   // prev iter's readers of buf[cur^1] are done -> safe to overwrite
        if (t + 1 < nt) { STAGE(t + 1, cur ^ 1); WAITV(4); }
        else            { WAITV(0); }

        const int co = cur * 512;
        short8v fa[4], fb[4];
        #pragma unroll
        for (int mi = 0; mi < 4; ++mi) fa[mi] = ((const short8v*)lA)[co + aslot[mi]];
        #pragma unroll
        for (int ni = 0; ni < 4; ++ni) fb[ni] = ((const short8v*)lB)[co + bslot[ni]];
        __builtin_amdgcn_s_setprio(1);
        #pragma unroll
        for (int mi = 0; mi < 4; ++mi)
            #pragma unroll
            for (int ni = 0; ni < 4; ++ni)
                acc[mi][ni] = __builtin_amdgcn_mfma_f32_16x16x32_bf16(fa[mi], fb[ni], acc[mi][ni], 0, 0, 0);
        __builtin_amdgcn_s_setprio(0);
    }

    const int fq = lane >> 4;
    if (isQK) {
        #pragma unroll
        for (int mi = 0; mi < 4; ++mi)
            #pragma unroll
            for (int ni = 0; ni < 4; ++ni)
                #pragma unroll
                for (int r = 0; r < 4; ++r) {
                    const int rg = bm + wr * 64 + mi * 16 + fq * 4 + r;
                    const int cg = bn + wc * 64 + ni * 16 + fr;
                    const u16 hh = f2bf(acc[mi][ni][r]);
                    if (cg < CC) Qo[(size_t)rg * CC + cg] = hh;
                    else         Ko[(size_t)rg * CC + cg - CC] = hh;
                }
    } else {
        // Vt output: rg = h*64+d (row of Wv), cg = b*2048+t
        #pragma unroll
        for (int mi = 0; mi < 4; ++mi)
            #pragma unroll
            for (int ni = 0; ni < 4; ++ni)
                #pragma unroll
                for (int r = 0; r < 4; ++r) {
                    const int rg = bm + wr * 64 + mi * 16 + fq * 4 + r;
                    const int cg = bn + wc * 64 + ni * 16 + fr;
                    const int bq = cg >> 11, tq = cg & 2047;
                    const int hq = rg >> 6, dq = rg & 63;
                    VtO[((size_t)((bq << 4) + hq) * HS + dq) * TT + tq] = f2bf(acc[mi][ni][r]);
                }
        // per-qt column sums: wave wc covers qt = ((bn + wc*64)&2047)>>6
        __syncthreads();                 // all LDS frag reads done -> reuse lA
        float* TSL = (float*)lA;         // 256 floats: [wc][row 0..127]
        #pragma unroll
        for (int mi = 0; mi < 4; ++mi)
            #pragma unroll
            for (int r = 0; r < 4; ++r) {
                float s = acc[mi][0][r] + acc[mi][1][r] + acc[mi][2][r] + acc[mi][3][r];
                s += __shfl_xor(s, 1); s += __shfl_xor(s, 2);
                s += __shfl_xor(s, 4); s += __shfl_xor(s, 8);
                if (fr == 0) TSL[wc * 128 + wr * 64 + mi * 16 + fq * 4 + r] = s;
            }
        __syncthreads();
        {
            const int wcq = tid >> 7, row = tid & 127;
            const int col0 = bn + wcq * 64;
            const int bq = col0 >> 11, qtv = (col0 & 2047) >> 6;
            const int bhh = (bq << 4) + ((bm + row) >> 6);
            const int dq = (bm + row) & 63;
            TSg[((size_t)bhh * QTILES + qtv) * 64 + dq] = TSL[tid];
        }
    }
}

// ---------------- suffix scan over tile sums -> STile ----------------
__global__ __launch_bounds__(64) void scan_kernel(const float* __restrict__ TSg,
                                                  float* __restrict__ STile) {
    const int bh = blockIdx.x;
    const int d = threadIdx.x;
    float s = 0.f;
    STile[((size_t)bh * 33 + 32) * 64 + d] = 0.f;
    for (int qt = QTILES - 1; qt >= 0; --qt) {
        s += TSg[((size_t)bh * QTILES + qt) * 64 + d];
        STile[((size_t)bh * 33 + qt) * 64 + d] = s;
    }
}

// ---------------- proj GEMM (bf16 in, fp32 out) ----------------
__global__ __launch_bounds__(256) void gemm_proj(const u16* __restrict__ A, const u16* __restrict__ B,
                                                 float* __restrict__ O, int M, int N, int K) {
    constexpr int GNT = 64;
    __shared__ u16 lA[2 * 4096], lB[2 * GNT * 32];
    const int tid = threadIdx.x;
    const int lane = tid & 63, w = tid >> 6;
    const int wr = w >> 1, wc = w & 1;
    const int fr = lane & 15, fc = lane >> 4;

    const int nbx = gridDim.x;
    const int bid = blockIdx.y * nbx + blockIdx.x;
    const int nwg = nbx * gridDim.y;
    const int swz = (bid & 7) * (nwg >> 3) + (bid >> 3);
    const int bm = (swz / nbx) * 128, bn = (swz % nbx) * GNT;

    f32x4 acc[4][2];
    #pragma unroll
    for (int i = 0; i < 4; ++i)
        #pragma unroll
        for (int j = 0; j < 2; ++j) acc[i][j] = (f32x4){0.f, 0.f, 0.f, 0.f};

    const int lrow = lane >> 2, lcs = lane & 3;
    const int rA0 = w * 16 + lrow, rA1 = rA0 + 64;
    const size_t aoff0 = (size_t)(bm + rA0) * K + (lcs ^ ((rA0 >> 1) & 3)) * 8;
    const size_t aoff1 = (size_t)(bm + rA1) * K + (lcs ^ ((rA1 >> 1) & 3)) * 8;
    const size_t boff0 = (size_t)(bn + rA0) * K + (lcs ^ ((rA0 >> 1) & 3)) * 8;
    const int d0 = w * 512, d1 = 2048 + w * 512;

    int aslot[4], bslot[2];
    #pragma unroll
    for (int mi = 0; mi < 4; ++mi) {
        int row = wr * 64 + mi * 16 + fr;
        aslot[mi] = row * 4 + (fc ^ ((row >> 1) & 3));
    }
    #pragma unroll
    for (int ni = 0; ni < 2; ++ni) {
        int col = wc * 32 + ni * 16 + fr;
        bslot[ni] = col * 4 + (fc ^ ((col >> 1) & 3));
    }

    auto STAGE = [&](int t, int buf) {
        const int k0 = t * 32;
        const int bo = buf * 4096;
        glds16(A + aoff0 + k0, lA + bo + d0);
        glds16(A + aoff1 + k0, lA + bo + d1);
        const int bo2 = buf * 2048;
        glds16(B + boff0 + k0, lB + bo2 + d0);
    };

    const int nt = K >> 5;
    STAGE(0, 0);

    #pragma unroll 2
    for (int t = 0; t < nt; ++t) {
        const int cur = t & 1;
        BAR();
        if (t + 1 < nt) { STAGE(t + 1, cur ^ 1); WAITV(3); }
        else            { WAITV(0); }

        const int co = cur * 512, co2 = cur * 256;
        short8v fa[4], fb[2];
        #pragma unroll
        for (int mi = 0; mi < 4; ++mi) fa[mi] = ((const short8v*)lA)[co + aslot[mi]];
        #pragma unroll
        for (int ni = 0; ni < 2; ++ni) fb[ni] = ((const short8v*)lB)[co2 + bslot[ni]];
        __builtin_amdgcn_s_setprio(1);
        #pragma unroll
        for (int mi = 0; mi < 4; ++mi)
            #pragma unroll
            for (int ni = 0; ni < 2; ++ni)
                acc[mi][ni] = __builtin_amdgcn_mfma_f32_16x16x32_bf16(fa[mi], fb[ni], acc[mi][ni], 0, 0, 0);
        __builtin_amdgcn_s_setprio(0);
    }

    const int fq = lane >> 4;
    #pragma unroll
    for (int mi = 0; mi < 4; ++mi)
        #pragma unroll
        for (int ni = 0; ni < 2; ++ni)
            #pragma unroll
            for (int r = 0; r < 4; ++r) {
                const int rg = bm + wr * 64 + mi * 16 + fq * 4 + r;
                const int cg = bn + wc * 32 + ni * 16 + fr;
                O[(size_t)rg * N + cg] = acc[mi][ni][r];
            }
}

// ---------------- MFMA flash attention (R3-PROVEN): 1 q-tile/block, K dbuf, V single-buf ----------------
// 1024 blocks = 32 bh x 32 qt; big qt dispatched first; bh locked to one XCD.
// 4 waves; wave w owns q-rows [w*16, w*16+16). Static max M=0; -U folded into y via
// negated causal ones MFMA on the diagonal tile; + STile at the end.
__global__ __launch_bounds__(256, 4) void attn_kernel(const u16* __restrict__ Qh,
                                                      const u16* __restrict__ Kh,
                                                      const u16* __restrict__ Vt,
                                                      const float* __restrict__ STile,
                                                      u16* __restrict__ Yh) {
    const int g = blockIdx.x;            // 1024
    const int bh = (g & 7) + 8 * ((g >> 3) & 3);   // bh locked to one XCD
    const int qt = 31 - (g >> 5);                  // big tiles first in dispatch order
    const int b = bh >> 4, h = bh & 15;
    const int tid = threadIdx.x;
    const int w = tid >> 6, lane = tid & 63;
    const int lx = lane & 15, hi4 = lane >> 4;

    __shared__ u16 Ksh[2 * 4096];   // 16KB: K dbuf
    __shared__ u16 Vsh[4096];       // 8KB: V single buffer

    const u16* Kg = Kh + (size_t)b * TT * CC + h * HS;
    const u16* Vg = Vt + (size_t)bh * HS * TT;

    // staging geometry: chunk s = w*64 + lane (+256); linear dest, source col pre-swizzled
    const int s0 = w * 64 + lane, s1 = 256 + w * 64 + lane;
    const int rr0 = s0 >> 3, gc0 = (s0 & 7) ^ (rr0 & 7);
    const int rr1 = s1 >> 3, gc1 = (s1 & 7) ^ (rr1 & 7);
    const int db0 = (w * 64) * 8, db1 = (256 + w * 64) * 8;
    const size_t kbase0 = (size_t)rr0 * CC + gc0 * 8;
    const size_t kbase1 = (size_t)rr1 * CC + gc1 * 8;
    const size_t vbase0 = (size_t)rr0 * TT + gc0 * 8;
    const size_t vbase1 = (size_t)rr1 * TT + gc1 * 8;

    auto stage_K = [&](int kt, int buf) {
        const size_t ko = (size_t)kt * 64 * CC;
        const int bo = buf * 4096;
        glds16(Kg + ko + kbase0, Ksh + bo + db0);
        glds16(Kg + ko + kbase1, Ksh + bo + db1);
    };
    auto stage_V = [&](int kt) {
        const int vo = kt * 64;
        glds16(Vg + vbase0 + vo, Vsh + db0);
        glds16(Vg + vbase1 + vo, Vsh + db1);
    };

    // NEGATED causal-inclusive ones A-frags (fold -U into y on the diagonal tile)
    short8v nones[2];
    #pragma unroll
    for (int k0 = 0; k0 < 2; ++k0)
        #pragma unroll
        for (int jj = 0; jj < 8; ++jj)
            nones[k0][jj] = (short)(((k0 * 32 + hi4 * 8 + jj) <= (w * 16 + lx)) ? 0xBF80 : 0);

    int cur = 0;
    stage_K(0, 0);

    const size_t qoff = (size_t)(b * TT + qt * 64 + w * 16 + lx) * CC + h * HS + hi4 * 8;
    short8v qf[2];
    qf[0] = *(const short8v*)(Qh + qoff); qf[1] = *(const short8v*)(Qh + qoff + 32);

    const f32x4 zero = {0.f, 0.f, 0.f, 0.f};
    f32x4 y4[4];
    float lsum = 0.f;
    #pragma unroll
    for (int dt = 0; dt < 4; ++dt) y4[dt] = zero;

    for (int kt = 0; kt <= qt; ++kt) {
        WAITV(0);   // own K(kt) (and V(kt-1)) drained -> landed
        BAR();      // everyone's K(kt) visible; prev PV readers of Vsh done
        stage_V(kt);
        if (kt < qt) stage_K(kt + 1, cur ^ 1);

        const int co = cur * 512;
        const bool diag = (kt == qt);

        // ---- QK^T (swapped: A=K, B=Q -> D = S^T) ----
        f32x4 s4[4];
        #pragma unroll
        for (int j = 0; j < 4; ++j) s4[j] = zero;
        __builtin_amdgcn_s_setprio(1);
        #pragma unroll
        for (int j = 0; j < 4; ++j) {
            const int keyr = j * 16 + lx;
            const int rb = keyr * 8, sw = keyr & 7;
            #pragma unroll
            for (int d0 = 0; d0 < 2; ++d0) {
                const short8v kb = ((const short8v*)Ksh)[co + rb + ((hi4 + 4 * d0) ^ sw)];
                s4[j] = __builtin_amdgcn_mfma_f32_16x16x32_bf16(kb, qf[d0], s4[j], 0, 0, 0);
            }
        }
        __builtin_amdgcn_s_setprio(0);

        // ---- softmax (static M=0): lane holds P[key=j*16+hi4*4+r][q=lx] ----
        unsigned Wpk[4][2];   // [j][h]: bf16 pair of adjacent keys
        #pragma unroll
        for (int j = 0; j < 4; ++j) {
            float pv[4];
            #pragma unroll
            for (int r = 0; r < 4; ++r) {
                float e = __builtin_amdgcn_exp2f(s4[j][r]);
                if (diag && (j * 16 + hi4 * 4 + r) > (w * 16 + lx)) e = 0.f;
                lsum += e;
                pv[r] = e;
            }
            Wpk[j][0] = (unsigned)f2bf(pv[0]) | ((unsigned)f2bf(pv[1]) << 16);
            Wpk[j][1] = (unsigned)f2bf(pv[2]) | ((unsigned)f2bf(pv[3]) << 16);
        }
        // ---- in-register P transpose: 2-stage permlane butterfly ----
        #pragma unroll
        for (int j1 = 0; j1 < 2; ++j1)
            #pragma unroll
            for (int hh = 0; hh < 2; ++hh) {
                swap32(Wpk[2 * j1][hh], Wpk[2 * j1 + 1][hh]);
                swap16(Wpk[2 * j1][hh], Wpk[2 * j1 + 1][hh]);
            }
        short8v pa[2];
        #pragma unroll
        for (int k0 = 0; k0 < 2; ++k0) {
            u32x4 ah = {Wpk[2 * k0][0], Wpk[2 * k0][1], Wpk[2 * k0 + 1][0], Wpk[2 * k0 + 1][1]};
            pa[k0] = __builtin_bit_cast(short8v, ah);
        }

        if (kt < qt) { WAITV(2); }   // drain V(kt); keep K(kt+1) in flight
        else         { WAITV(0); }
        BAR();   // everyone's V(kt) DMA landed -> Vsh complete

        // ---- PV (+ negated causal-ones on the diagonal tile) ----
        __builtin_amdgcn_s_setprio(1);
        #pragma unroll
        for (int dt = 0; dt < 4; ++dt) {
            const int drow = dt * 16 + lx;
            const int rb = drow * 8, sw = drow & 7;
            #pragma unroll
            for (int k0 = 0; k0 < 2; ++k0) {
                const short8v vb = ((const short8v*)Vsh)[rb + ((hi4 + 4 * k0) ^ sw)];
                y4[dt] = __builtin_amdgcn_mfma_f32_16x16x32_bf16(pa[k0], vb, y4[dt], 0, 0, 0);
                if (diag)
                    y4[dt] = __builtin_amdgcn_mfma_f32_16x16x32_bf16(nones[k0], vb, y4[dt], 0, 0, 0);
            }
        }
        __builtin_amdgcn_s_setprio(0);

        cur ^= 1;
    }

    // ---- l reduce: lsum is per-lane (q=lx); sum hi4 groups, redistribute to (hi4,r) ----
    lsum += __shfl_xor(lsum, 16);
    lsum += __shfl_xor(lsum, 32);
    float l4[4];
    #pragma unroll
    for (int r = 0; r < 4; ++r) l4[r] = __shfl(lsum, hi4 * 4 + r);

    // ---- masked-zero tail: y holds (PV - U); add STile, normalize ----
    const float* stp = STile + ((size_t)bh * 33 + qt) * 64;
    #pragma unroll
    for (int dt = 0; dt < 4; ++dt) {
        const float st = stp[dt * 16 + lx];
        #pragma unroll
        for (int r = 0; r < 4; ++r) {
            const int t = qt * 64 + w * 16 + hi4 * 4 + r;
            const float linv = 1.f / (l4[r] + (float)(TT - 1 - t));
            const float yv = (y4[dt][r] + st) * linv;
            const size_t off = (size_t)(b * TT + t) * CC + h * HS + dt * 16 + lx;
            Yh[off] = f2bf(yv);
        }
    }
}

// ---------------- launch ----------------
extern "C" void kernel_launch(void* const* d_in, const int* in_sizes, int n_in,
                              void* d_out, int out_size, void* d_ws, size_t ws_size,
                              hipStream_t stream) {
    const float* x  = (const float*)d_in[0];
    const float* Wq = (const float*)d_in[1];
    const float* Wk = (const float*)d_in[2];
    const float* Wv = (const float*)d_in[3];
    const float* Wp = (const float*)d_in[4];
    float* out = (float*)d_out;

    char* ws = (char*)d_ws;
    // [0,8MB): x bf16; after qkv x is dead -> Y bf16
    u16* xh = (u16*)ws;
    u16* Yh = xh;
    // [16,24MB): Q bf16; [32,40MB): K bf16
    u16* Qh = (u16*)(ws + (16u << 20));
    u16* Kh = (u16*)(ws + (32u << 20));
    // [48,50MB): Wv bf16; [52,+256KB): TSg; [56,58MB): Wp bf16
    u16* wv = (u16*)(ws + (48u << 20));
    float* TSg = (float*)(ws + (52u << 20));
    u16* wp = (u16*)(ws + (56u << 20));
    // [64MB,+270KB): STile
    float* St = (float*)(ws + (64u << 20));
    // d_out (16MB): wqk [0,4MB), Vt [4,12MB) (both dead before proj overwrites)
    u16* wqk = (u16*)out;
    u16* Vth = (u16*)((char*)out + (4u << 20));

    fsplit_kernel<<<8192, 256, 0, stream>>>(x, Wq, Wk, Wv, Wp, xh, wqk, wv, wp);

    // merged QK GEMM (512 blocks) + V^T GEMM (256 blocks)
    qkv_kernel<<<768, 256, 0, stream>>>(xh, wqk, wv, Qh, Kh, Vth, TSg);

    scan_kernel<<<BB * HH, 64, 0, stream>>>(TSg, St);

    attn_kernel<<<1024, 256, 0, stream>>>(Qh, Kh, Vth, St, Yh);

    // output projection (overwrites d_out; wqk/Vt dead)
    gemm_proj<<<dim3(CC / 64, NROWS / 128), 256, 0, stream>>>(Yh, wp, out, NROWS, CC, CC);
}